// Round 3
// baseline (17088.553 us; speedup 1.0000x reference)
//
#include <hip/hip_runtime.h>
#include <math.h>

#define N_NODES 200000
#define N_EDGES 800000
#define N_GRAPHS 8192
#define ECAP 384

typedef unsigned short ushort_t;

__device__ __forceinline__ float selu_f(float x){
  const float alpha = 1.6732632423543772f;
  const float lam   = 1.0507009873554805f;
  return x > 0.f ? lam * x : lam * alpha * (expf(x) - 1.f);
}

// ---------------- utility ----------------
__global__ void zero_i32(int* p, int n){
  int i = blockIdx.x * 256 + threadIdx.x;
  if (i < n) p[i] = 0;
}

// ---------------- CSR build ----------------
__global__ void deg_kernel(const int* __restrict__ dst, int* __restrict__ deg, int E){
  int e = blockIdx.x * 256 + threadIdx.x;
  if (e < E) atomicAdd(&deg[dst[e]], 1);
}

__global__ void scan1(const int* __restrict__ deg, int* __restrict__ rp, int* __restrict__ bs, int n){
  __shared__ int sh[256];
  int t = threadIdx.x;
  int base = blockIdx.x * 1024;
  int v[4]; int s = 0;
  #pragma unroll
  for (int i = 0; i < 4; i++){
    int idx = base + t * 4 + i;
    v[i] = (idx < n) ? deg[idx] : 0;
    s += v[i];
  }
  sh[t] = s; __syncthreads();
  for (int off = 1; off < 256; off <<= 1){
    int x = (t >= off) ? sh[t - off] : 0;
    __syncthreads();
    sh[t] += x;
    __syncthreads();
  }
  int run = (t == 0) ? 0 : sh[t - 1];
  #pragma unroll
  for (int i = 0; i < 4; i++){
    int idx = base + t * 4 + i;
    if (idx < n) rp[idx] = run;
    run += v[i];
  }
  if (t == 255) bs[blockIdx.x] = sh[255];
}

__global__ void scan2(int* bs, int nb){
  __shared__ int sh[256];
  int t = threadIdx.x;
  sh[t] = (t < nb) ? bs[t] : 0; __syncthreads();
  for (int off = 1; off < 256; off <<= 1){
    int x = (t >= off) ? sh[t - off] : 0;
    __syncthreads();
    sh[t] += x;
    __syncthreads();
  }
  int excl = (t == 0) ? 0 : sh[t - 1];
  if (t < nb) bs[t] = excl;
}

__global__ void scan3(int* rp, const int* __restrict__ bs, int n, int total){
  int i = blockIdx.x * 256 + threadIdx.x;
  if (i < n) rp[i] += bs[i >> 10];
  if (i == 0) rp[n] = total;
}

__global__ void fill_csr(const int* __restrict__ src, const int* __restrict__ dst,
                         const int* __restrict__ rp, int* __restrict__ fil,
                         int* __restrict__ csr, int E){
  int e = blockIdx.x * 256 + threadIdx.x;
  if (e < E){
    int d = dst[e];
    int p = atomicAdd(&fil[d], 1);
    csr[rp[d] + p] = src[e];
  }
}

// ---------------- V = attn^T W precompute ----------------
// V1: [4][128], V2: [4][256], V3: [256]
__global__ void compute_v(const float* __restrict__ W1, const float* __restrict__ al1, const float* __restrict__ ar1,
                          const float* __restrict__ W2, const float* __restrict__ al2, const float* __restrict__ ar2,
                          const float* __restrict__ W3, const float* __restrict__ al3, const float* __restrict__ ar3,
                          float* __restrict__ V1L, float* __restrict__ V1R,
                          float* __restrict__ V2L, float* __restrict__ V2R,
                          float* __restrict__ V3L, float* __restrict__ V3R){
  int i = blockIdx.x * 256 + threadIdx.x;
  if (i < 512){
    int h = i >> 7, k = i & 127;
    float sl = 0.f, sr = 0.f;
    for (int dd = 0; dd < 64; dd++){
      float w = W1[(size_t)(h * 64 + dd) * 128 + k];
      sl += al1[h * 64 + dd] * w;
      sr += ar1[h * 64 + dd] * w;
    }
    V1L[i] = sl; V1R[i] = sr;
  } else if (i < 1536){
    int j = i - 512;
    int h = j >> 8, k = j & 255;
    float sl = 0.f, sr = 0.f;
    for (int dd = 0; dd < 64; dd++){
      float w = W2[(size_t)(h * 64 + dd) * 256 + k];
      sl += al2[h * 64 + dd] * w;
      sr += ar2[h * 64 + dd] * w;
    }
    V2L[j] = sl; V2R[j] = sr;
  } else if (i < 1792){
    int k = i - 1536;
    float sl = 0.f, sr = 0.f;
    for (int dd = 0; dd < 64; dd++){
      float w = W3[(size_t)dd * 256 + k];
      sl += al3[dd] * w;
      sr += ar3[dd] * w;
    }
    V3L[k] = sl; V3R[k] = sr;
  }
}

// ---------------- el/er for layer 1 (from raw input x0) ----------------
__global__ __launch_bounds__(256) void el_er1(const float* __restrict__ x0,
                                              const float* __restrict__ V1L, const float* __restrict__ V1R,
                                              float* __restrict__ el1, float* __restrict__ er1, int n){
  __shared__ float vl[512], vr[512];
  int t = threadIdx.x;
  for (int i = t; i < 512; i += 256){ vl[i] = V1L[i]; vr[i] = V1R[i]; }
  __syncthreads();
  int node = blockIdx.x * 4 + (t >> 6);
  int l = t & 63;
  if (node >= n) return;
  float xa = x0[(size_t)node * 128 + l];
  float xb = x0[(size_t)node * 128 + 64 + l];
  #pragma unroll
  for (int h = 0; h < 4; h++){
    float pl = xa * vl[h * 128 + l] + xb * vl[h * 128 + 64 + l];
    float pr = xa * vr[h * 128 + l] + xb * vr[h * 128 + 64 + l];
    #pragma unroll
    for (int off = 32; off; off >>= 1){ pl += __shfl_xor(pl, off); pr += __shfl_xor(pr, off); }
    if (l == 0){ el1[(size_t)node * 4 + h] = pl; er1[(size_t)node * 4 + h] = pr; }
  }
}

// ---------------- FUSED layer 1: agg(recompute feat1) -> x1 (24b split) + el2/er2 ----------------
__global__ __launch_bounds__(256, 1) void fused_l1(
    const float* __restrict__ x0, const float* __restrict__ W1, const float* __restrict__ bias1,
    const float* __restrict__ el1, const float* __restrict__ er1,
    const float* __restrict__ V2L, const float* __restrict__ V2R,
    const int* __restrict__ rp, const int* __restrict__ csr,
    ushort_t* __restrict__ x1hi, unsigned char* __restrict__ x1lo,
    float* __restrict__ el2, float* __restrict__ er2){
  __shared__ float x1s[64][257];
  __shared__ float Ws[128][128];     // Ws[k][c] = W1[half*128+c][k]
  __shared__ float als[ECAP][4];
  __shared__ int   ssrc[ECAP];
  __shared__ unsigned char dloc[ECAP];
  __shared__ float mds[64][4], idns[64][4], ers[64][4];
  int t = threadIdx.x;
  int nb0 = blockIdx.x * 64;

  // phase 0: per-dst m / 1/denom
  {
    int d = t >> 2, h = t & 3;
    int s0 = rp[nb0 + d], s1 = rp[nb0 + d + 1];
    float erv = er1[(size_t)(nb0 + d) * 4 + h];
    ers[d][h] = erv;
    float m = -1e30f;
    for (int i = s0; i < s1; i++){
      float e = el1[(size_t)csr[i] * 4 + h] + erv;
      e = e > 0.f ? e : 0.2f * e;
      m = fmaxf(m, e);
    }
    float den = 0.f;
    for (int i = s0; i < s1; i++){
      float e = el1[(size_t)csr[i] * 4 + h] + erv;
      e = e > 0.f ? e : 0.2f * e;
      den += expf(e - m);
    }
    mds[d][h] = m;
    idns[d][h] = (s1 > s0) ? 1.f / den : 0.f;
  }
  for (int i = t; i < 64 * 257; i += 256) ((float*)x1s)[i] = 0.f;
  __syncthreads();

  int e0 = rp[nb0], eN = rp[nb0 + 64];
  for (int half = 0; half < 2; half++){
    // stage W half, transposed
    for (int i = t; i < 128 * 32; i += 256){
      int r = i >> 5, k4 = i & 31;
      float4 w = *reinterpret_cast<const float4*>(W1 + (size_t)(half * 128 + r) * 128 + k4 * 4);
      Ws[k4 * 4 + 0][r] = w.x;
      Ws[k4 * 4 + 1][r] = w.y;
      Ws[k4 * 4 + 2][r] = w.z;
      Ws[k4 * 4 + 3][r] = w.w;
    }
    __syncthreads();
    for (int c0 = e0; c0 < eN; c0 += ECAP){
      int ce = min(ECAP, eN - c0);
      for (int i = t; i < ce; i += 256) ssrc[i] = csr[c0 + i];
      {
        int d = t >> 2, h = t & 3;
        if (h == 0){
          int s0 = rp[nb0 + d], s1 = rp[nb0 + d + 1];
          int lo = max(s0, c0), hi2 = min(s1, c0 + ce);
          for (int g = lo; g < hi2; g++) dloc[g - c0] = (unsigned char)d;
        }
      }
      __syncthreads();
      for (int i = t; i < ce; i += 256){
        int s = ssrc[i]; int d = dloc[i];
        #pragma unroll
        for (int h = 0; h < 4; h++){
          float e = el1[(size_t)s * 4 + h] + ers[d][h];
          e = e > 0.f ? e : 0.2f * e;
          als[i][h] = expf(e - mds[d][h]) * idns[d][h];
        }
      }
      __syncthreads();
      // dot: 8 edges per iter; thread: c=t&127, g=t>>7 -> edges j+4g+m
      int c = t & 127, g = t >> 7;
      int hc = half * 128 + c;
      int h = hc >> 6;
      for (int j = 0; j < ce; j += 8){
        int eb = j + 4 * g;
        const float* r0 = x0 + (size_t)ssrc[min(eb + 0, ce - 1)] * 128;
        const float* r1 = x0 + (size_t)ssrc[min(eb + 1, ce - 1)] * 128;
        const float* r2 = x0 + (size_t)ssrc[min(eb + 2, ce - 1)] * 128;
        const float* r3 = x0 + (size_t)ssrc[min(eb + 3, ce - 1)] * 128;
        float a0 = 0.f, a1 = 0.f, a2 = 0.f, a3 = 0.f;
        #pragma unroll 8
        for (int k4 = 0; k4 < 32; k4++){
          float4 v0 = reinterpret_cast<const float4*>(r0)[k4];
          float4 v1 = reinterpret_cast<const float4*>(r1)[k4];
          float4 v2 = reinterpret_cast<const float4*>(r2)[k4];
          float4 v3 = reinterpret_cast<const float4*>(r3)[k4];
          float w0 = Ws[k4 * 4 + 0][c], w1 = Ws[k4 * 4 + 1][c];
          float w2 = Ws[k4 * 4 + 2][c], w3 = Ws[k4 * 4 + 3][c];
          a0 += w0 * v0.x + w1 * v0.y + w2 * v0.z + w3 * v0.w;
          a1 += w0 * v1.x + w1 * v1.y + w2 * v1.z + w3 * v1.w;
          a2 += w0 * v2.x + w1 * v2.y + w2 * v2.z + w3 * v2.w;
          a3 += w0 * v3.x + w1 * v3.y + w2 * v3.z + w3 * v3.w;
        }
        if (eb + 0 < ce) atomicAdd(&x1s[dloc[eb + 0]][hc], als[eb + 0][h] * a0);
        if (eb + 1 < ce) atomicAdd(&x1s[dloc[eb + 1]][hc], als[eb + 1][h] * a1);
        if (eb + 2 < ce) atomicAdd(&x1s[dloc[eb + 2]][hc], als[eb + 2][h] * a2);
        if (eb + 3 < ce) atomicAdd(&x1s[dloc[eb + 3]][hc], als[eb + 3][h] * a3);
      }
      __syncthreads();
    }
  }
  // finalize: selu + 24-bit split store
  {
    int i = t & 63, q = t >> 6;
    for (int cc = 0; cc < 64; cc++){
      int col = q * 64 + cc;
      float v = selu_f(x1s[i][col] + bias1[col]);
      x1s[i][col] = v;
      unsigned int u = __float_as_uint(v);
      x1hi[(size_t)(nb0 + i) * 256 + col] = (ushort_t)(u >> 16);
      x1lo[(size_t)(nb0 + i) * 256 + col] = (unsigned char)(u >> 8);
    }
  }
  __syncthreads();
  // el2/er2 = V2 . x1
  {
    int i = t & 63, hh = t >> 6;
    float pl = 0.f, pr = 0.f;
    for (int k = 0; k < 256; k++){
      float xv = x1s[i][k];
      pl += xv * V2L[hh * 256 + k];
      pr += xv * V2R[hh * 256 + k];
    }
    el2[(size_t)(nb0 + i) * 4 + hh] = pl;
    er2[(size_t)(nb0 + i) * 4 + hh] = pr;
  }
}

// ---------------- FUSED layer 2: agg(recompute feat2) -> feat3 + el3/er3 (x2 never stored) ----------------
__global__ __launch_bounds__(256, 1) void fused_l2(
    const ushort_t* __restrict__ x1hi, const unsigned char* __restrict__ x1lo,
    const float* __restrict__ W2, const float* __restrict__ bias2,
    const float* __restrict__ el2, const float* __restrict__ er2,
    const float* __restrict__ W3,
    const float* __restrict__ V3L, const float* __restrict__ V3R,
    const int* __restrict__ rp, const int* __restrict__ csr,
    float* __restrict__ feat3, float* __restrict__ el3, float* __restrict__ er3){
  __shared__ float x2s[64][257];
  __shared__ float Ws2[256][64];      // Ws2[k][c] = W2[q*64+c][k] (also reused for W3)
  __shared__ float xrow[8][260];      // unpacked x1 rows for 8 edges
  __shared__ float als[ECAP][4];
  __shared__ int   ssrc[ECAP];
  __shared__ unsigned char dloc[ECAP];
  __shared__ float mds[64][4], idns[64][4], ers[64][4];
  int t = threadIdx.x;
  int nb0 = blockIdx.x * 64;

  // phase 0
  {
    int d = t >> 2, h = t & 3;
    int s0 = rp[nb0 + d], s1 = rp[nb0 + d + 1];
    float erv = er2[(size_t)(nb0 + d) * 4 + h];
    ers[d][h] = erv;
    float m = -1e30f;
    for (int i = s0; i < s1; i++){
      float e = el2[(size_t)csr[i] * 4 + h] + erv;
      e = e > 0.f ? e : 0.2f * e;
      m = fmaxf(m, e);
    }
    float den = 0.f;
    for (int i = s0; i < s1; i++){
      float e = el2[(size_t)csr[i] * 4 + h] + erv;
      e = e > 0.f ? e : 0.2f * e;
      den += expf(e - m);
    }
    mds[d][h] = m;
    idns[d][h] = (s1 > s0) ? 1.f / den : 0.f;
  }
  for (int i = t; i < 64 * 257; i += 256) ((float*)x2s)[i] = 0.f;
  __syncthreads();

  int e0 = rp[nb0], eN = rp[nb0 + 64];
  for (int q = 0; q < 4; q++){
    // stage W2 quarter, transposed: rows q*64..q*64+63
    for (int i = t; i < 64 * 64; i += 256){
      int r = i >> 6, k4 = i & 63;
      float4 w = *reinterpret_cast<const float4*>(W2 + (size_t)(q * 64 + r) * 256 + k4 * 4);
      Ws2[k4 * 4 + 0][r] = w.x;
      Ws2[k4 * 4 + 1][r] = w.y;
      Ws2[k4 * 4 + 2][r] = w.z;
      Ws2[k4 * 4 + 3][r] = w.w;
    }
    __syncthreads();
    for (int c0 = e0; c0 < eN; c0 += ECAP){
      int ce = min(ECAP, eN - c0);
      for (int i = t; i < ce; i += 256) ssrc[i] = csr[c0 + i];
      {
        int d = t >> 2, h = t & 3;
        if (h == 0){
          int s0 = rp[nb0 + d], s1 = rp[nb0 + d + 1];
          int lo = max(s0, c0), hi2 = min(s1, c0 + ce);
          for (int g = lo; g < hi2; g++) dloc[g - c0] = (unsigned char)d;
        }
      }
      __syncthreads();
      for (int i = t; i < ce; i += 256){
        int s = ssrc[i]; int d = dloc[i];
        #pragma unroll
        for (int h = 0; h < 4; h++){
          float e = el2[(size_t)s * 4 + h] + ers[d][h];
          e = e > 0.f ? e : 0.2f * e;
          als[i][h] = expf(e - mds[d][h]) * idns[d][h];
        }
      }
      __syncthreads();
      for (int j = 0; j < ce; j += 8){
        // stage 8 x1 rows unpacked to fp32
        {
          int et = t >> 5, seg = t & 31;            // 8 edges x 32 segs x 8 elems
          int e = j + et;
          int s = ssrc[min(e, ce - 1)];
          const ushort_t* hp = x1hi + (size_t)s * 256 + seg * 8;
          const unsigned char* lp = x1lo + (size_t)s * 256 + seg * 8;
          #pragma unroll
          for (int ii = 0; ii < 8; ii++){
            unsigned int u = ((unsigned int)hp[ii] << 16) | ((unsigned int)lp[ii] << 8);
            xrow[et][seg * 8 + ii] = __uint_as_float(u);
          }
        }
        __syncthreads();
        int c = t & 63, g = t >> 6;      // edges j + 2g + {0,1}
        int eb = j + 2 * g;
        float a0 = 0.f, a1 = 0.f;
        #pragma unroll 8
        for (int k = 0; k < 256; k++){
          float w = Ws2[k][c];
          a0 += w * xrow[2 * g + 0][k];
          a1 += w * xrow[2 * g + 1][k];
        }
        if (eb + 0 < ce) atomicAdd(&x2s[dloc[eb + 0]][q * 64 + c], als[eb + 0][q] * a0);
        if (eb + 1 < ce) atomicAdd(&x2s[dloc[eb + 1]][q * 64 + c], als[eb + 1][q] * a1);
        __syncthreads();
      }
      __syncthreads();
    }
  }
  // finalize x2 = selu(agg + bias2)
  {
    int i = t & 63, q = t >> 6;
    for (int cc = 0; cc < 64; cc++){
      int col = q * 64 + cc;
      x2s[i][col] = selu_f(x2s[i][col] + bias2[col]);
    }
  }
  __syncthreads();
  // feat3 = W3 . x2 ; stage W3 transposed into Ws2
  for (int i = t; i < 64 * 64; i += 256){
    int r = i >> 6, k4 = i & 63;
    float4 w = *reinterpret_cast<const float4*>(W3 + (size_t)r * 256 + k4 * 4);
    Ws2[k4 * 4 + 0][r] = w.x;
    Ws2[k4 * 4 + 1][r] = w.y;
    Ws2[k4 * 4 + 2][r] = w.z;
    Ws2[k4 * 4 + 3][r] = w.w;
  }
  __syncthreads();
  {
    int c = t & 63, dg = t >> 6;
    for (int d = dg; d < 64; d += 4){
      float acc = 0.f;
      for (int k = 0; k < 256; k++) acc += Ws2[k][c] * x2s[d][k];
      feat3[(size_t)(nb0 + d) * 64 + c] = acc;
    }
  }
  // el3/er3
  {
    int i = t & 63, jj = t >> 6;
    if (jj == 0){
      float p = 0.f;
      for (int k = 0; k < 256; k++) p += x2s[i][k] * V3L[k];
      el3[nb0 + i] = p;
    } else if (jj == 1){
      float p = 0.f;
      for (int k = 0; k < 256; k++) p += x2s[i][k] * V3R[k];
      er3[nb0 + i] = p;
    }
  }
}

// ---------------- layer-3 aggregation (feat3 stored, H=1) ----------------
__global__ void gat_agg3(const float* __restrict__ feat, const float* __restrict__ el,
                         const float* __restrict__ er, const int* __restrict__ rp,
                         const int* __restrict__ csr, const float* __restrict__ bias,
                         float* __restrict__ out, int n){
  int node = blockIdx.x;
  int t = threadIdx.x;  // 0..63
  int start = rp[node], end = rp[node + 1];
  float erv = er[node];
  float m = -1e30f;
  for (int i = start; i < end; i++){
    float e = el[csr[i]] + erv;
    e = e > 0.f ? e : 0.2f * e;
    m = fmaxf(m, e);
  }
  float denom = 0.f, acc = 0.f;
  for (int i = start; i < end; i++){
    int s = csr[i];
    float e = el[s] + erv;
    e = e > 0.f ? e : 0.2f * e;
    float a = expf(e - m);
    denom += a;
    acc += a * feat[(size_t)s * 64 + t];
  }
  float o = (end > start) ? acc / denom : 0.f;
  o += bias[t];
  out[(size_t)node * 64 + t] = selu_f(o);
}

// ---------------- readout ----------------
__global__ void readout_kernel(const float* __restrict__ x3, const float* __restrict__ score_w,
                               const float* __restrict__ score_b, const int* __restrict__ gids,
                               float* __restrict__ num, float* __restrict__ den, int n){
  int node = blockIdx.x * 4 + (threadIdx.x >> 6);
  int lane = threadIdx.x & 63;
  if (node >= n) return;
  float xv = x3[(size_t)node * 64 + lane];
  float p = xv * score_w[lane];
  #pragma unroll
  for (int off = 32; off; off >>= 1) p += __shfl_xor(p, off);
  float w = 1.f / (1.f + expf(-(p + score_b[0])));
  int g = gids[node];
  atomicAdd(&num[(size_t)g * 64 + lane], w * xv);
  if (lane == 0) atomicAdd(&den[g], w);
}

// ---------------- final MLP ----------------
__global__ __launch_bounds__(128) void mlp_kernel(
    const float* __restrict__ num, const float* __restrict__ den,
    const float* __restrict__ fg,
    const float* __restrict__ w1, const float* __restrict__ b1,
    const float* __restrict__ w2, const float* __restrict__ b2,
    const float* __restrict__ w3, const float* __restrict__ b3,
    float* __restrict__ out, int G){
  __shared__ float z[80];
  __shared__ float h1[128];
  __shared__ float h2[64];
  int t = threadIdx.x;
  for (int g = blockIdx.x; g < G; g += gridDim.x){
    if (t < 64){
      float d = den[g];
      d = (d == 0.f) ? 1.f : d;
      z[t] = num[(size_t)g * 64 + t] / d;
    } else if (t < 80){
      z[t] = fg[(size_t)g * 16 + (t - 64)];
    }
    __syncthreads();
    {
      float a = b1[t];
      for (int k = 0; k < 80; k++) a += z[k] * w1[t * 80 + k];
      h1[t] = selu_f(a);
    }
    __syncthreads();
    if (t < 64){
      float a = b2[t];
      for (int k = 0; k < 128; k++) a += h1[k] * w2[t * 128 + k];
      h2[t] = selu_f(a);
    }
    __syncthreads();
    if (t < 64){
      float p = h2[t] * w3[t];
      #pragma unroll
      for (int off = 32; off; off >>= 1) p += __shfl_down(p, off);
      if (t == 0) out[g] = p + b3[0];
    }
    __syncthreads();
  }
}

// ---------------- launch ----------------
extern "C" void kernel_launch(void* const* d_in, const int* in_sizes, int n_in,
                              void* d_out, int out_size, void* d_ws, size_t ws_size,
                              hipStream_t stream) {
  const float* feats_node  = (const float*)d_in[0];
  const float* feats_graph = (const float*)d_in[1];
  const int*   src         = (const int*)d_in[2];
  const int*   dst         = (const int*)d_in[3];
  const int*   gids        = (const int*)d_in[4];
  const float* fc1_w   = (const float*)d_in[5];
  const float* attn_l1 = (const float*)d_in[6];
  const float* attn_r1 = (const float*)d_in[7];
  const float* bias1   = (const float*)d_in[8];
  const float* fc2_w   = (const float*)d_in[9];
  const float* attn_l2 = (const float*)d_in[10];
  const float* attn_r2 = (const float*)d_in[11];
  const float* bias2   = (const float*)d_in[12];
  const float* fc3_w   = (const float*)d_in[13];
  const float* attn_l3 = (const float*)d_in[14];
  const float* attn_r3 = (const float*)d_in[15];
  const float* bias3   = (const float*)d_in[16];
  const float* score_w = (const float*)d_in[17];
  const float* score_b = (const float*)d_in[18];
  const float* mlp_w1  = (const float*)d_in[19];
  const float* mlp_b1  = (const float*)d_in[20];
  const float* mlp_w2  = (const float*)d_in[21];
  const float* mlp_b2  = (const float*)d_in[22];
  const float* mlp_w3  = (const float*)d_in[23];
  const float* mlp_b3  = (const float*)d_in[24];
  float* out = (float*)d_out;

  char* ws = (char*)d_ws;
  size_t off = 0;
  auto alloc = [&](size_t bytes) -> void* {
    void* p = ws + off;
    off += (bytes + 255) / 256 * 256;
    return p;
  };
  int*   deg  = (int*)alloc((size_t)N_NODES * 4);
  int*   fil  = (int*)alloc((size_t)N_NODES * 4);
  int*   rp   = (int*)alloc((size_t)(N_NODES + 1) * 4);
  int*   bs   = (int*)alloc(256 * 4);
  int*   csr  = (int*)alloc((size_t)N_EDGES * 4);
  float* el1  = (float*)alloc((size_t)N_NODES * 4 * 4);
  float* er1  = (float*)alloc((size_t)N_NODES * 4 * 4);
  float* el2  = (float*)alloc((size_t)N_NODES * 4 * 4);
  float* er2  = (float*)alloc((size_t)N_NODES * 4 * 4);
  float* el3  = (float*)alloc((size_t)N_NODES * 4);
  float* er3  = (float*)alloc((size_t)N_NODES * 4);
  float* V1L  = (float*)alloc(512 * 4);
  float* V1R  = (float*)alloc(512 * 4);
  float* V2L  = (float*)alloc(1024 * 4);
  float* V2R  = (float*)alloc(1024 * 4);
  float* V3L  = (float*)alloc(256 * 4);
  float* V3R  = (float*)alloc(256 * 4);
  float* num  = (float*)alloc((size_t)N_GRAPHS * 64 * 4);
  float* den  = (float*)alloc((size_t)N_GRAPHS * 4);
  float* feat3 = (float*)alloc((size_t)N_NODES * 64 * 4);
  ushort_t*      x1hi = (ushort_t*)alloc((size_t)N_NODES * 256 * 2);  // 102.4MB
  unsigned char* x1lo = (unsigned char*)alloc((size_t)N_NODES * 256); //  51.2MB
  float* x3 = (float*)x1hi;  // overlay: x1hi dead after fused_l2

  // zero accumulators
  zero_i32<<<(N_NODES + 255) / 256, 256, 0, stream>>>(deg, N_NODES);
  zero_i32<<<(N_NODES + 255) / 256, 256, 0, stream>>>(fil, N_NODES);
  zero_i32<<<(N_GRAPHS * 64 + 255) / 256, 256, 0, stream>>>((int*)num, N_GRAPHS * 64);
  zero_i32<<<(N_GRAPHS + 255) / 256, 256, 0, stream>>>((int*)den, N_GRAPHS);

  // CSR build (by dst)
  deg_kernel<<<(N_EDGES + 255) / 256, 256, 0, stream>>>(dst, deg, N_EDGES);
  scan1<<<196, 256, 0, stream>>>(deg, rp, bs, N_NODES);
  scan2<<<1, 256, 0, stream>>>(bs, 196);
  scan3<<<(N_NODES + 255) / 256, 256, 0, stream>>>(rp, bs, N_NODES, N_EDGES);
  fill_csr<<<(N_EDGES + 255) / 256, 256, 0, stream>>>(src, dst, rp, fil, csr, N_EDGES);

  // V precompute + layer-1 logits
  compute_v<<<7, 256, 0, stream>>>(fc1_w, attn_l1, attn_r1, fc2_w, attn_l2, attn_r2,
                                   fc3_w, attn_l3, attn_r3, V1L, V1R, V2L, V2R, V3L, V3R);
  el_er1<<<N_NODES / 4, 256, 0, stream>>>(feats_node, V1L, V1R, el1, er1, N_NODES);

  // fused layers
  fused_l1<<<N_NODES / 64, 256, 0, stream>>>(feats_node, fc1_w, bias1, el1, er1,
                                             V2L, V2R, rp, csr, x1hi, x1lo, el2, er2);
  fused_l2<<<N_NODES / 64, 256, 0, stream>>>(x1hi, x1lo, fc2_w, bias2, el2, er2,
                                             fc3_w, V3L, V3R, rp, csr, feat3, el3, er3);
  gat_agg3<<<N_NODES, 64, 0, stream>>>(feat3, el3, er3, rp, csr, bias3, x3, N_NODES);

  // readout + MLP
  readout_kernel<<<N_NODES / 4, 256, 0, stream>>>(x3, score_w, score_b, gids, num, den, N_NODES);
  mlp_kernel<<<256, 128, 0, stream>>>(num, den, feats_graph,
                                      mlp_w1, mlp_b1, mlp_w2, mlp_b2, mlp_w3, mlp_b3,
                                      out, N_GRAPHS);
}

// Round 4
// 5445.018 us; speedup vs baseline: 3.1384x; 3.1384x over previous
//
#include <hip/hip_runtime.h>
#include <math.h>

#define N_NODES 200000
#define N_EDGES 800000
#define N_GRAPHS 8192
#define EC 256      // edge chunk per block
#define B1 32       // dst nodes per block, layer-1 fused
#define B2 16       // dst nodes per block, layer-2 fused

typedef unsigned short ushort_t;

__device__ __forceinline__ float selu_f(float x){
  const float alpha = 1.6732632423543772f;
  const float lam   = 1.0507009873554805f;
  return x > 0.f ? lam * x : lam * alpha * (expf(x) - 1.f);
}

// ---------------- utility ----------------
__global__ void zero_i32(int* p, int n){
  int i = blockIdx.x * 256 + threadIdx.x;
  if (i < n) p[i] = 0;
}

// ---------------- CSR build ----------------
__global__ void deg_kernel(const int* __restrict__ dst, int* __restrict__ deg, int E){
  int e = blockIdx.x * 256 + threadIdx.x;
  if (e < E) atomicAdd(&deg[dst[e]], 1);
}

__global__ void scan1(const int* __restrict__ deg, int* __restrict__ rp, int* __restrict__ bs, int n){
  __shared__ int sh[256];
  int t = threadIdx.x;
  int base = blockIdx.x * 1024;
  int v[4]; int s = 0;
  #pragma unroll
  for (int i = 0; i < 4; i++){
    int idx = base + t * 4 + i;
    v[i] = (idx < n) ? deg[idx] : 0;
    s += v[i];
  }
  sh[t] = s; __syncthreads();
  for (int off = 1; off < 256; off <<= 1){
    int x = (t >= off) ? sh[t - off] : 0;
    __syncthreads();
    sh[t] += x;
    __syncthreads();
  }
  int run = (t == 0) ? 0 : sh[t - 1];
  #pragma unroll
  for (int i = 0; i < 4; i++){
    int idx = base + t * 4 + i;
    if (idx < n) rp[idx] = run;
    run += v[i];
  }
  if (t == 255) bs[blockIdx.x] = sh[255];
}

__global__ void scan2(int* bs, int nb){
  __shared__ int sh[256];
  int t = threadIdx.x;
  sh[t] = (t < nb) ? bs[t] : 0; __syncthreads();
  for (int off = 1; off < 256; off <<= 1){
    int x = (t >= off) ? sh[t - off] : 0;
    __syncthreads();
    sh[t] += x;
    __syncthreads();
  }
  int excl = (t == 0) ? 0 : sh[t - 1];
  if (t < nb) bs[t] = excl;
}

__global__ void scan3(int* rp, const int* __restrict__ bs, int n, int total){
  int i = blockIdx.x * 256 + threadIdx.x;
  if (i < n) rp[i] += bs[i >> 10];
  if (i == 0) rp[n] = total;
}

__global__ void fill_csr(const int* __restrict__ src, const int* __restrict__ dst,
                         const int* __restrict__ rp, int* __restrict__ fil,
                         int* __restrict__ csr, int E){
  int e = blockIdx.x * 256 + threadIdx.x;
  if (e < E){
    int d = dst[e];
    int p = atomicAdd(&fil[d], 1);
    csr[rp[d] + p] = src[e];
  }
}

// ---------------- V = attn^T W precompute ----------------
__global__ void compute_v(const float* __restrict__ W1, const float* __restrict__ al1, const float* __restrict__ ar1,
                          const float* __restrict__ W2, const float* __restrict__ al2, const float* __restrict__ ar2,
                          const float* __restrict__ W3, const float* __restrict__ al3, const float* __restrict__ ar3,
                          float* __restrict__ V1L, float* __restrict__ V1R,
                          float* __restrict__ V2L, float* __restrict__ V2R,
                          float* __restrict__ V3L, float* __restrict__ V3R){
  int i = blockIdx.x * 256 + threadIdx.x;
  if (i < 512){
    int h = i >> 7, k = i & 127;
    float sl = 0.f, sr = 0.f;
    for (int dd = 0; dd < 64; dd++){
      float w = W1[(size_t)(h * 64 + dd) * 128 + k];
      sl += al1[h * 64 + dd] * w;
      sr += ar1[h * 64 + dd] * w;
    }
    V1L[i] = sl; V1R[i] = sr;
  } else if (i < 1536){
    int j = i - 512;
    int h = j >> 8, k = j & 255;
    float sl = 0.f, sr = 0.f;
    for (int dd = 0; dd < 64; dd++){
      float w = W2[(size_t)(h * 64 + dd) * 256 + k];
      sl += al2[h * 64 + dd] * w;
      sr += ar2[h * 64 + dd] * w;
    }
    V2L[j] = sl; V2R[j] = sr;
  } else if (i < 1792){
    int k = i - 1536;
    float sl = 0.f, sr = 0.f;
    for (int dd = 0; dd < 64; dd++){
      float w = W3[(size_t)dd * 256 + k];
      sl += al3[dd] * w;
      sr += ar3[dd] * w;
    }
    V3L[k] = sl; V3R[k] = sr;
  }
}

// ---------------- el/er for layer 1 ----------------
__global__ __launch_bounds__(256) void el_er1(const float* __restrict__ x0,
                                              const float* __restrict__ V1L, const float* __restrict__ V1R,
                                              float* __restrict__ el1, float* __restrict__ er1, int n){
  __shared__ float vl[512], vr[512];
  int t = threadIdx.x;
  for (int i = t; i < 512; i += 256){ vl[i] = V1L[i]; vr[i] = V1R[i]; }
  __syncthreads();
  int node = blockIdx.x * 4 + (t >> 6);
  int l = t & 63;
  if (node >= n) return;
  float xa = x0[(size_t)node * 128 + l];
  float xb = x0[(size_t)node * 128 + 64 + l];
  #pragma unroll
  for (int h = 0; h < 4; h++){
    float pl = xa * vl[h * 128 + l] + xb * vl[h * 128 + 64 + l];
    float pr = xa * vr[h * 128 + l] + xb * vr[h * 128 + 64 + l];
    #pragma unroll
    for (int off = 32; off; off >>= 1){ pl += __shfl_xor(pl, off); pr += __shfl_xor(pr, off); }
    if (l == 0){ el1[(size_t)node * 4 + h] = pl; er1[(size_t)node * 4 + h] = pr; }
  }
}

// ---------------- FUSED layer 1: per-head agg(x0) -> GEMM W1 -> x1(24b) + el2/er2 ----------------
__global__ __launch_bounds__(512, 1) void l1_fused(
    const float* __restrict__ x0, const float* __restrict__ W1, const float* __restrict__ bias1,
    const float* __restrict__ el1, const float* __restrict__ er1,
    const float* __restrict__ V2L, const float* __restrict__ V2R,
    const int* __restrict__ rp, const int* __restrict__ csr,
    ushort_t* __restrict__ x1hi, unsigned char* __restrict__ x1lo,
    float* __restrict__ el2, float* __restrict__ er2){
  __shared__ float agg[4][B1][129];    // [head][dst][k]  66048B
  __shared__ float Ws[64][129];        // W1 row-chunk     33024B
  __shared__ float x1s[B1][257];       //                  32896B
  __shared__ float als[EC][4];
  __shared__ int   ssrc[EC];
  __shared__ unsigned char dloc[EC];
  __shared__ float mds[B1][4], idns[B1][4], ers[B1][4];
  int t = threadIdx.x;
  int nb0 = blockIdx.x * B1;

  // phase A: per-(dst,head) softmax stats
  if (t < B1 * 4){
    int d = t >> 2, h = t & 3;
    int s0 = rp[nb0 + d], s1 = rp[nb0 + d + 1];
    float erv = er1[(size_t)(nb0 + d) * 4 + h];
    ers[d][h] = erv;
    float m = -1e30f;
    for (int i = s0; i < s1; i++){
      float e = el1[(size_t)csr[i] * 4 + h] + erv;
      e = e > 0.f ? e : 0.2f * e;
      m = fmaxf(m, e);
    }
    float den = 0.f;
    for (int i = s0; i < s1; i++){
      float e = el1[(size_t)csr[i] * 4 + h] + erv;
      e = e > 0.f ? e : 0.2f * e;
      den += expf(e - m);
    }
    mds[d][h] = m;
    idns[d][h] = (s1 > s0) ? 1.f / den : 0.f;
  }
  for (int i = t; i < 4 * B1 * 129; i += 512) ((float*)agg)[i] = 0.f;
  __syncthreads();

  int e0 = rp[nb0], eN = rp[nb0 + B1];
  for (int c0 = e0; c0 < eN; c0 += EC){
    int ce = min(EC, eN - c0);
    for (int i = t; i < ce; i += 512) ssrc[i] = csr[c0 + i];
    if (t < B1){
      int s0 = rp[nb0 + t], s1 = rp[nb0 + t + 1];
      int lo = max(s0, c0) - c0, hi = min(s1, c0 + ce) - c0;
      for (int i = lo; i < hi; i++) dloc[i] = (unsigned char)t;
    }
    __syncthreads();
    for (int i = t; i < ce; i += 512){
      int s = ssrc[i]; int d = dloc[i];
      #pragma unroll
      for (int h = 0; h < 4; h++){
        float e = el1[(size_t)s * 4 + h] + ers[d][h];
        e = e > 0.f ? e : 0.2f * e;
        als[i][h] = expf(e - mds[d][h]) * idns[d][h];
      }
    }
    __syncthreads();
    // gather: 4 groups of 128 threads; group g handles dsts d%4==g
    {
      int c = t & 127, g = t >> 7;
      for (int d = g; d < B1; d += 4){
        int lo = max(rp[nb0 + d], c0) - c0;
        int hi = min(rp[nb0 + d + 1], c0 + ce) - c0;
        if (lo >= hi) continue;
        float a0 = agg[0][d][c], a1 = agg[1][d][c], a2 = agg[2][d][c], a3 = agg[3][d][c];
        for (int i = lo; i < hi; i++){
          float xv = x0[(size_t)ssrc[i] * 128 + c];
          a0 += als[i][0] * xv;
          a1 += als[i][1] * xv;
          a2 += als[i][2] * xv;
          a3 += als[i][3] * xv;
        }
        agg[0][d][c] = a0; agg[1][d][c] = a1; agg[2][d][c] = a2; agg[3][d][c] = a3;
      }
    }
    __syncthreads();
  }

  // GEMM: x1[d][m] = selu( sum_k W1[m,k] * agg[h(m)][d][k] + b1[m] )
  for (int ch = 0; ch < 4; ch++){          // output rows ch*64..+63, head = ch
    for (int i = t; i < 64 * 32; i += 512){
      int r = i >> 5, k4 = i & 31;
      float4 w = *reinterpret_cast<const float4*>(W1 + (size_t)(ch * 64 + r) * 128 + k4 * 4);
      Ws[r][k4 * 4 + 0] = w.x; Ws[r][k4 * 4 + 1] = w.y;
      Ws[r][k4 * 4 + 2] = w.z; Ws[r][k4 * 4 + 3] = w.w;
    }
    __syncthreads();
    {
      int d = t & 31, mg = t >> 5;     // mg 0..15
      #pragma unroll
      for (int j = 0; j < 4; j++){
        int m = mg + j * 16;
        float s = 0.f;
        #pragma unroll 4
        for (int k = 0; k < 128; k++) s += Ws[m][k] * agg[ch][d][k];
        int col = ch * 64 + m;
        x1s[d][col] = selu_f(s + bias1[col]);
      }
    }
    __syncthreads();
  }

  // el2/er2 from fp32 x1 tile
  if (t < 256){
    int d = t & 31, hq = (t >> 5) & 3, lr = t >> 7;
    const float* V = lr ? V2R : V2L;
    float s = 0.f;
    for (int k = 0; k < 256; k++) s += V[hq * 256 + k] * x1s[d][k];
    if (lr) er2[(size_t)(nb0 + d) * 4 + hq] = s;
    else    el2[(size_t)(nb0 + d) * 4 + hq] = s;
  }
  // 24-bit split store
  for (int i = t; i < B1 * 256; i += 512){
    int r = i >> 8, col = i & 255;
    unsigned int u = __float_as_uint(x1s[r][col]);
    x1hi[(size_t)(nb0 + r) * 256 + col] = (ushort_t)(u >> 16);
    x1lo[(size_t)(nb0 + r) * 256 + col] = (unsigned char)(u >> 8);
  }
}

// ---------------- FUSED layer 2: per-head agg(x1) -> W2 GEMM -> x2(LDS) -> el3/er3 + feat3 ----------------
__global__ __launch_bounds__(512, 1) void l2_fused(
    const ushort_t* __restrict__ x1hi, const unsigned char* __restrict__ x1lo,
    const float* __restrict__ W2, const float* __restrict__ bias2,
    const float* __restrict__ el2, const float* __restrict__ er2,
    const float* __restrict__ W3,
    const float* __restrict__ V3L, const float* __restrict__ V3R,
    const int* __restrict__ rp, const int* __restrict__ csr,
    float* __restrict__ feat3, float* __restrict__ el3, float* __restrict__ er3){
  __shared__ float agg[4][B2][257];    // 65792B ; reused as W3s[64][257] at tail
  __shared__ float Wc[32][257];        // 32896B
  __shared__ float x2s[B2][257];       // 16448B
  __shared__ float als[EC][4];
  __shared__ int   ssrc[EC];
  __shared__ unsigned char dloc[EC];
  __shared__ float mds[B2][4], idns[B2][4], ers[B2][4];
  int t = threadIdx.x;
  int nb0 = blockIdx.x * B2;

  if (t < B2 * 4){
    int d = t >> 2, h = t & 3;
    int s0 = rp[nb0 + d], s1 = rp[nb0 + d + 1];
    float erv = er2[(size_t)(nb0 + d) * 4 + h];
    ers[d][h] = erv;
    float m = -1e30f;
    for (int i = s0; i < s1; i++){
      float e = el2[(size_t)csr[i] * 4 + h] + erv;
      e = e > 0.f ? e : 0.2f * e;
      m = fmaxf(m, e);
    }
    float den = 0.f;
    for (int i = s0; i < s1; i++){
      float e = el2[(size_t)csr[i] * 4 + h] + erv;
      e = e > 0.f ? e : 0.2f * e;
      den += expf(e - m);
    }
    mds[d][h] = m;
    idns[d][h] = (s1 > s0) ? 1.f / den : 0.f;
  }
  for (int i = t; i < 4 * B2 * 257; i += 512) ((float*)agg)[i] = 0.f;
  __syncthreads();

  int e0 = rp[nb0], eN = rp[nb0 + B2];
  for (int c0 = e0; c0 < eN; c0 += EC){
    int ce = min(EC, eN - c0);
    for (int i = t; i < ce; i += 512) ssrc[i] = csr[c0 + i];
    if (t < B2){
      int s0 = rp[nb0 + t], s1 = rp[nb0 + t + 1];
      int lo = max(s0, c0) - c0, hi = min(s1, c0 + ce) - c0;
      for (int i = lo; i < hi; i++) dloc[i] = (unsigned char)t;
    }
    __syncthreads();
    for (int i = t; i < ce; i += 512){
      int s = ssrc[i]; int d = dloc[i];
      #pragma unroll
      for (int h = 0; h < 4; h++){
        float e = el2[(size_t)s * 4 + h] + ers[d][h];
        e = e > 0.f ? e : 0.2f * e;
        als[i][h] = expf(e - mds[d][h]) * idns[d][h];
      }
    }
    __syncthreads();
    // gather x1 (24-bit), 2 groups of 256 threads
    {
      int c = t & 255, g = t >> 8;
      for (int d = g; d < B2; d += 2){
        int lo = max(rp[nb0 + d], c0) - c0;
        int hi = min(rp[nb0 + d + 1], c0 + ce) - c0;
        if (lo >= hi) continue;
        float a0 = agg[0][d][c], a1 = agg[1][d][c], a2 = agg[2][d][c], a3 = agg[3][d][c];
        for (int i = lo; i < hi; i++){
          size_t s = (size_t)ssrc[i] * 256 + c;
          unsigned int u = ((unsigned int)x1hi[s] << 16) | ((unsigned int)x1lo[s] << 8);
          float xv = __uint_as_float(u);
          a0 += als[i][0] * xv;
          a1 += als[i][1] * xv;
          a2 += als[i][2] * xv;
          a3 += als[i][3] * xv;
        }
        agg[0][d][c] = a0; agg[1][d][c] = a1; agg[2][d][c] = a2; agg[3][d][c] = a3;
      }
    }
    __syncthreads();
  }

  // GEMM: x2[d][col] = selu( sum_k W2[col,k]*agg[h][d][k] + b2 ), 8 chunks of 32 rows
  for (int ch = 0; ch < 8; ch++){
    for (int i = t; i < 32 * 64; i += 512){
      int r = i >> 6, k4 = i & 63;
      float4 w = *reinterpret_cast<const float4*>(W2 + (size_t)(ch * 32 + r) * 256 + k4 * 4);
      Wc[r][k4 * 4 + 0] = w.x; Wc[r][k4 * 4 + 1] = w.y;
      Wc[r][k4 * 4 + 2] = w.z; Wc[r][k4 * 4 + 3] = w.w;
    }
    __syncthreads();
    {
      int d = t & 15, m = t >> 4;      // m 0..31
      int h = ch >> 1;
      float s = 0.f;
      #pragma unroll 4
      for (int k = 0; k < 256; k++) s += Wc[m][k] * agg[h][d][k];
      int col = ch * 32 + m;
      x2s[d][col] = selu_f(s + bias2[col]);
    }
    __syncthreads();
  }

  // stage W3 into agg region (agg dead)
  float* W3s = (float*)agg;            // [64][257]
  for (int i = t; i < 64 * 64; i += 512){
    int r = i >> 6, k4 = i & 63;
    float4 w = *reinterpret_cast<const float4*>(W3 + (size_t)r * 256 + k4 * 4);
    W3s[r * 257 + k4 * 4 + 0] = w.x; W3s[r * 257 + k4 * 4 + 1] = w.y;
    W3s[r * 257 + k4 * 4 + 2] = w.z; W3s[r * 257 + k4 * 4 + 3] = w.w;
  }
  __syncthreads();
  // el3/er3 from fp32 x2 tile
  if (t < 32){
    int d = t & 15, lr = t >> 4;
    const float* V = lr ? V3R : V3L;
    float s = 0.f;
    for (int k = 0; k < 256; k++) s += V[k] * x2s[d][k];
    if (lr) er3[nb0 + d] = s;
    else    el3[nb0 + d] = s;
  }
  // feat3 = W3 . x2
  #pragma unroll
  for (int j = 0; j < 2; j++){
    int idx = t + j * 512;
    int d = idx >> 6, c = idx & 63;
    float s = 0.f;
    #pragma unroll 4
    for (int k = 0; k < 256; k++) s += W3s[c * 257 + k] * x2s[d][k];
    feat3[(size_t)(nb0 + d) * 64 + c] = s;
  }
}

// ---------------- layer-3 aggregation (H=1) ----------------
__global__ void gat_agg3(const float* __restrict__ feat, const float* __restrict__ el,
                         const float* __restrict__ er, const int* __restrict__ rp,
                         const int* __restrict__ csr, const float* __restrict__ bias,
                         float* __restrict__ out, int n){
  int node = blockIdx.x;
  int t = threadIdx.x;  // 0..63
  int start = rp[node], end = rp[node + 1];
  float erv = er[node];
  float m = -1e30f;
  for (int i = start; i < end; i++){
    float e = el[csr[i]] + erv;
    e = e > 0.f ? e : 0.2f * e;
    m = fmaxf(m, e);
  }
  float denom = 0.f, acc = 0.f;
  for (int i = start; i < end; i++){
    int s = csr[i];
    float e = el[s] + erv;
    e = e > 0.f ? e : 0.2f * e;
    float a = expf(e - m);
    denom += a;
    acc += a * feat[(size_t)s * 64 + t];
  }
  float o = (end > start) ? acc / denom : 0.f;
  o += bias[t];
  out[(size_t)node * 64 + t] = selu_f(o);
}

// ---------------- readout ----------------
__global__ void readout_kernel(const float* __restrict__ x3, const float* __restrict__ score_w,
                               const float* __restrict__ score_b, const int* __restrict__ gids,
                               float* __restrict__ num, float* __restrict__ den, int n){
  int node = blockIdx.x * 4 + (threadIdx.x >> 6);
  int lane = threadIdx.x & 63;
  if (node >= n) return;
  float xv = x3[(size_t)node * 64 + lane];
  float p = xv * score_w[lane];
  #pragma unroll
  for (int off = 32; off; off >>= 1) p += __shfl_xor(p, off);
  float w = 1.f / (1.f + expf(-(p + score_b[0])));
  int g = gids[node];
  atomicAdd(&num[(size_t)g * 64 + lane], w * xv);
  if (lane == 0) atomicAdd(&den[g], w);
}

// ---------------- final MLP ----------------
__global__ __launch_bounds__(128) void mlp_kernel(
    const float* __restrict__ num, const float* __restrict__ den,
    const float* __restrict__ fg,
    const float* __restrict__ w1, const float* __restrict__ b1,
    const float* __restrict__ w2, const float* __restrict__ b2,
    const float* __restrict__ w3, const float* __restrict__ b3,
    float* __restrict__ out, int G){
  __shared__ float z[80];
  __shared__ float h1[128];
  __shared__ float h2[64];
  int t = threadIdx.x;
  for (int g = blockIdx.x; g < G; g += gridDim.x){
    if (t < 64){
      float d = den[g];
      d = (d == 0.f) ? 1.f : d;
      z[t] = num[(size_t)g * 64 + t] / d;
    } else if (t < 80){
      z[t] = fg[(size_t)g * 16 + (t - 64)];
    }
    __syncthreads();
    {
      float a = b1[t];
      for (int k = 0; k < 80; k++) a += z[k] * w1[t * 80 + k];
      h1[t] = selu_f(a);
    }
    __syncthreads();
    if (t < 64){
      float a = b2[t];
      for (int k = 0; k < 128; k++) a += h1[k] * w2[t * 128 + k];
      h2[t] = selu_f(a);
    }
    __syncthreads();
    if (t < 64){
      float p = h2[t] * w3[t];
      #pragma unroll
      for (int off = 32; off; off >>= 1) p += __shfl_down(p, off);
      if (t == 0) out[g] = p + b3[0];
    }
    __syncthreads();
  }
}

// ---------------- launch ----------------
extern "C" void kernel_launch(void* const* d_in, const int* in_sizes, int n_in,
                              void* d_out, int out_size, void* d_ws, size_t ws_size,
                              hipStream_t stream) {
  const float* feats_node  = (const float*)d_in[0];
  const float* feats_graph = (const float*)d_in[1];
  const int*   src         = (const int*)d_in[2];
  const int*   dst         = (const int*)d_in[3];
  const int*   gids        = (const int*)d_in[4];
  const float* fc1_w   = (const float*)d_in[5];
  const float* attn_l1 = (const float*)d_in[6];
  const float* attn_r1 = (const float*)d_in[7];
  const float* bias1   = (const float*)d_in[8];
  const float* fc2_w   = (const float*)d_in[9];
  const float* attn_l2 = (const float*)d_in[10];
  const float* attn_r2 = (const float*)d_in[11];
  const float* bias2   = (const float*)d_in[12];
  const float* fc3_w   = (const float*)d_in[13];
  const float* attn_l3 = (const float*)d_in[14];
  const float* attn_r3 = (const float*)d_in[15];
  const float* bias3   = (const float*)d_in[16];
  const float* score_w = (const float*)d_in[17];
  const float* score_b = (const float*)d_in[18];
  const float* mlp_w1  = (const float*)d_in[19];
  const float* mlp_b1  = (const float*)d_in[20];
  const float* mlp_w2  = (const float*)d_in[21];
  const float* mlp_b2  = (const float*)d_in[22];
  const float* mlp_w3  = (const float*)d_in[23];
  const float* mlp_b3  = (const float*)d_in[24];
  float* out = (float*)d_out;

  char* ws = (char*)d_ws;
  size_t off = 0;
  auto alloc = [&](size_t bytes) -> void* {
    void* p = ws + off;
    off += (bytes + 255) / 256 * 256;
    return p;
  };
  int*   deg  = (int*)alloc((size_t)N_NODES * 4);
  int*   fil  = (int*)alloc((size_t)N_NODES * 4);
  int*   rp   = (int*)alloc((size_t)(N_NODES + 1) * 4);
  int*   bs   = (int*)alloc(256 * 4);
  int*   csr  = (int*)alloc((size_t)N_EDGES * 4);
  float* el1  = (float*)alloc((size_t)N_NODES * 4 * 4);
  float* er1  = (float*)alloc((size_t)N_NODES * 4 * 4);
  float* el2  = (float*)alloc((size_t)N_NODES * 4 * 4);
  float* er2  = (float*)alloc((size_t)N_NODES * 4 * 4);
  float* el3  = (float*)alloc((size_t)N_NODES * 4);
  float* er3  = (float*)alloc((size_t)N_NODES * 4);
  float* V1L  = (float*)alloc(512 * 4);
  float* V1R  = (float*)alloc(512 * 4);
  float* V2L  = (float*)alloc(1024 * 4);
  float* V2R  = (float*)alloc(1024 * 4);
  float* V3L  = (float*)alloc(256 * 4);
  float* V3R  = (float*)alloc(256 * 4);
  float* num  = (float*)alloc((size_t)N_GRAPHS * 64 * 4);
  float* den  = (float*)alloc((size_t)N_GRAPHS * 4);
  float* feat3 = (float*)alloc((size_t)N_NODES * 64 * 4);
  ushort_t*      x1hi = (ushort_t*)alloc((size_t)N_NODES * 256 * 2);
  unsigned char* x1lo = (unsigned char*)alloc((size_t)N_NODES * 256);
  float* x3 = (float*)x1hi;  // overlay: x1 dead after l2_fused

  zero_i32<<<(N_NODES + 255) / 256, 256, 0, stream>>>(deg, N_NODES);
  zero_i32<<<(N_NODES + 255) / 256, 256, 0, stream>>>(fil, N_NODES);
  zero_i32<<<(N_GRAPHS * 64 + 255) / 256, 256, 0, stream>>>((int*)num, N_GRAPHS * 64);
  zero_i32<<<(N_GRAPHS + 255) / 256, 256, 0, stream>>>((int*)den, N_GRAPHS);

  deg_kernel<<<(N_EDGES + 255) / 256, 256, 0, stream>>>(dst, deg, N_EDGES);
  scan1<<<196, 256, 0, stream>>>(deg, rp, bs, N_NODES);
  scan2<<<1, 256, 0, stream>>>(bs, 196);
  scan3<<<(N_NODES + 255) / 256, 256, 0, stream>>>(rp, bs, N_NODES, N_EDGES);
  fill_csr<<<(N_EDGES + 255) / 256, 256, 0, stream>>>(src, dst, rp, fil, csr, N_EDGES);

  compute_v<<<7, 256, 0, stream>>>(fc1_w, attn_l1, attn_r1, fc2_w, attn_l2, attn_r2,
                                   fc3_w, attn_l3, attn_r3, V1L, V1R, V2L, V2R, V3L, V3R);
  el_er1<<<N_NODES / 4, 256, 0, stream>>>(feats_node, V1L, V1R, el1, er1, N_NODES);

  l1_fused<<<N_NODES / B1, 512, 0, stream>>>(feats_node, fc1_w, bias1, el1, er1,
                                             V2L, V2R, rp, csr, x1hi, x1lo, el2, er2);
  l2_fused<<<N_NODES / B2, 512, 0, stream>>>(x1hi, x1lo, fc2_w, bias2, el2, er2,
                                             fc3_w, V3L, V3R, rp, csr, feat3, el3, er3);
  gat_agg3<<<N_NODES, 64, 0, stream>>>(feat3, el3, er3, rp, csr, bias3, x3, N_NODES);

  readout_kernel<<<N_NODES / 4, 256, 0, stream>>>(x3, score_w, score_b, gids, num, den, N_NODES);
  mlp_kernel<<<256, 128, 0, stream>>>(num, den, feats_graph,
                                      mlp_w1, mlp_b1, mlp_w2, mlp_b2, mlp_w3, mlp_b3,
                                      out, N_GRAPHS);
}

// Round 5
// 3996.435 us; speedup vs baseline: 4.2759x; 1.3625x over previous
//
#include <hip/hip_runtime.h>
#include <math.h>

#define N_NODES 200000
#define N_EDGES 800000
#define N_GRAPHS 8192
#define B1 16       // dst nodes per block, layer-1 fused
#define EC1 128
#define B2G 16      // dst nodes per block, layer-2 gather
#define EC2 128

typedef unsigned short ushort_t;

__device__ __forceinline__ float selu_f(float x){
  const float alpha = 1.6732632423543772f;
  const float lam   = 1.0507009873554805f;
  return x > 0.f ? lam * x : lam * alpha * (expf(x) - 1.f);
}

// ---------------- utility ----------------
__global__ void zero_i32(int* p, int n){
  int i = blockIdx.x * 256 + threadIdx.x;
  if (i < n) p[i] = 0;
}

// ---------------- CSR build ----------------
__global__ void deg_kernel(const int* __restrict__ dst, int* __restrict__ deg, int E){
  int e = blockIdx.x * 256 + threadIdx.x;
  if (e < E) atomicAdd(&deg[dst[e]], 1);
}

__global__ void scan1(const int* __restrict__ deg, int* __restrict__ rp, int* __restrict__ bs, int n){
  __shared__ int sh[256];
  int t = threadIdx.x;
  int base = blockIdx.x * 1024;
  int v[4]; int s = 0;
  #pragma unroll
  for (int i = 0; i < 4; i++){
    int idx = base + t * 4 + i;
    v[i] = (idx < n) ? deg[idx] : 0;
    s += v[i];
  }
  sh[t] = s; __syncthreads();
  for (int off = 1; off < 256; off <<= 1){
    int x = (t >= off) ? sh[t - off] : 0;
    __syncthreads();
    sh[t] += x;
    __syncthreads();
  }
  int run = (t == 0) ? 0 : sh[t - 1];
  #pragma unroll
  for (int i = 0; i < 4; i++){
    int idx = base + t * 4 + i;
    if (idx < n) rp[idx] = run;
    run += v[i];
  }
  if (t == 255) bs[blockIdx.x] = sh[255];
}

__global__ void scan2(int* bs, int nb){
  __shared__ int sh[256];
  int t = threadIdx.x;
  sh[t] = (t < nb) ? bs[t] : 0; __syncthreads();
  for (int off = 1; off < 256; off <<= 1){
    int x = (t >= off) ? sh[t - off] : 0;
    __syncthreads();
    sh[t] += x;
    __syncthreads();
  }
  int excl = (t == 0) ? 0 : sh[t - 1];
  if (t < nb) bs[t] = excl;
}

__global__ void scan3(int* rp, const int* __restrict__ bs, int n, int total){
  int i = blockIdx.x * 256 + threadIdx.x;
  if (i < n) rp[i] += bs[i >> 10];
  if (i == 0) rp[n] = total;
}

__global__ void fill_csr(const int* __restrict__ src, const int* __restrict__ dst,
                         const int* __restrict__ rp, int* __restrict__ fil,
                         int* __restrict__ csr, int E){
  int e = blockIdx.x * 256 + threadIdx.x;
  if (e < E){
    int d = dst[e];
    int p = atomicAdd(&fil[d], 1);
    csr[rp[d] + p] = src[e];
  }
}

// ---------------- V = attn^T W precompute ----------------
__global__ void compute_v(const float* __restrict__ W1, const float* __restrict__ al1, const float* __restrict__ ar1,
                          const float* __restrict__ W2, const float* __restrict__ al2, const float* __restrict__ ar2,
                          const float* __restrict__ W3, const float* __restrict__ al3, const float* __restrict__ ar3,
                          float* __restrict__ V1L, float* __restrict__ V1R,
                          float* __restrict__ V2L, float* __restrict__ V2R,
                          float* __restrict__ V3L, float* __restrict__ V3R){
  int i = blockIdx.x * 256 + threadIdx.x;
  if (i < 512){
    int h = i >> 7, k = i & 127;
    float sl = 0.f, sr = 0.f;
    for (int dd = 0; dd < 64; dd++){
      float w = W1[(size_t)(h * 64 + dd) * 128 + k];
      sl += al1[h * 64 + dd] * w;
      sr += ar1[h * 64 + dd] * w;
    }
    V1L[i] = sl; V1R[i] = sr;
  } else if (i < 1536){
    int j = i - 512;
    int h = j >> 8, k = j & 255;
    float sl = 0.f, sr = 0.f;
    for (int dd = 0; dd < 64; dd++){
      float w = W2[(size_t)(h * 64 + dd) * 256 + k];
      sl += al2[h * 64 + dd] * w;
      sr += ar2[h * 64 + dd] * w;
    }
    V2L[j] = sl; V2R[j] = sr;
  } else if (i < 1792){
    int k = i - 1536;
    float sl = 0.f, sr = 0.f;
    for (int dd = 0; dd < 64; dd++){
      float w = W3[(size_t)dd * 256 + k];
      sl += al3[dd] * w;
      sr += ar3[dd] * w;
    }
    V3L[k] = sl; V3R[k] = sr;
  }
}

// ---------------- el/er for layer 1 ----------------
__global__ __launch_bounds__(256) void el_er1(const float* __restrict__ x0,
                                              const float* __restrict__ V1L, const float* __restrict__ V1R,
                                              float* __restrict__ el1, float* __restrict__ er1, int n){
  __shared__ float vl[512], vr[512];
  int t = threadIdx.x;
  for (int i = t; i < 512; i += 256){ vl[i] = V1L[i]; vr[i] = V1R[i]; }
  __syncthreads();
  int node = blockIdx.x * 4 + (t >> 6);
  int l = t & 63;
  if (node >= n) return;
  float xa = x0[(size_t)node * 128 + l];
  float xb = x0[(size_t)node * 128 + 64 + l];
  #pragma unroll
  for (int h = 0; h < 4; h++){
    float pl = xa * vl[h * 128 + l] + xb * vl[h * 128 + 64 + l];
    float pr = xa * vr[h * 128 + l] + xb * vr[h * 128 + 64 + l];
    #pragma unroll
    for (int off = 32; off; off >>= 1){ pl += __shfl_xor(pl, off); pr += __shfl_xor(pr, off); }
    if (l == 0){ el1[(size_t)node * 4 + h] = pl; er1[(size_t)node * 4 + h] = pr; }
  }
}

// ---------------- alpha kernels: per-dst softmax over edges, H=4 / H=1 ----------------
__global__ __launch_bounds__(256) void alpha_h4(const float* __restrict__ el, const float* __restrict__ er,
                                                const int* __restrict__ rp, const int* __restrict__ csr,
                                                float* __restrict__ a, int n){
  int node = blockIdx.x * 256 + threadIdx.x;
  if (node >= n) return;
  int s0 = rp[node], s1 = rp[node + 1];
  if (s0 >= s1) return;
  float4 erv = *reinterpret_cast<const float4*>(er + (size_t)node * 4);
  float m0 = -1e30f, m1 = -1e30f, m2 = -1e30f, m3 = -1e30f;
  for (int i = s0; i < s1; i++){
    float4 e = *reinterpret_cast<const float4*>(el + (size_t)csr[i] * 4);
    float e0 = e.x + erv.x; e0 = e0 > 0.f ? e0 : 0.2f * e0; m0 = fmaxf(m0, e0);
    float e1 = e.y + erv.y; e1 = e1 > 0.f ? e1 : 0.2f * e1; m1 = fmaxf(m1, e1);
    float e2 = e.z + erv.z; e2 = e2 > 0.f ? e2 : 0.2f * e2; m2 = fmaxf(m2, e2);
    float e3 = e.w + erv.w; e3 = e3 > 0.f ? e3 : 0.2f * e3; m3 = fmaxf(m3, e3);
  }
  float d0 = 0.f, d1 = 0.f, d2 = 0.f, d3 = 0.f;
  for (int i = s0; i < s1; i++){
    float4 e = *reinterpret_cast<const float4*>(el + (size_t)csr[i] * 4);
    float e0 = e.x + erv.x; e0 = e0 > 0.f ? e0 : 0.2f * e0; d0 += expf(e0 - m0);
    float e1 = e.y + erv.y; e1 = e1 > 0.f ? e1 : 0.2f * e1; d1 += expf(e1 - m1);
    float e2 = e.z + erv.z; e2 = e2 > 0.f ? e2 : 0.2f * e2; d2 += expf(e2 - m2);
    float e3 = e.w + erv.w; e3 = e3 > 0.f ? e3 : 0.2f * e3; d3 += expf(e3 - m3);
  }
  d0 = 1.f / d0; d1 = 1.f / d1; d2 = 1.f / d2; d3 = 1.f / d3;
  for (int i = s0; i < s1; i++){
    float4 e = *reinterpret_cast<const float4*>(el + (size_t)csr[i] * 4);
    float4 o;
    float e0 = e.x + erv.x; e0 = e0 > 0.f ? e0 : 0.2f * e0; o.x = expf(e0 - m0) * d0;
    float e1 = e.y + erv.y; e1 = e1 > 0.f ? e1 : 0.2f * e1; o.y = expf(e1 - m1) * d1;
    float e2 = e.z + erv.z; e2 = e2 > 0.f ? e2 : 0.2f * e2; o.z = expf(e2 - m2) * d2;
    float e3 = e.w + erv.w; e3 = e3 > 0.f ? e3 : 0.2f * e3; o.w = expf(e3 - m3) * d3;
    *reinterpret_cast<float4*>(a + (size_t)i * 4) = o;
  }
}

__global__ __launch_bounds__(256) void alpha_h1(const float* __restrict__ el, const float* __restrict__ er,
                                                const int* __restrict__ rp, const int* __restrict__ csr,
                                                float* __restrict__ a, int n){
  int node = blockIdx.x * 256 + threadIdx.x;
  if (node >= n) return;
  int s0 = rp[node], s1 = rp[node + 1];
  if (s0 >= s1) return;
  float erv = er[node];
  float m = -1e30f;
  for (int i = s0; i < s1; i++){
    float e = el[csr[i]] + erv; e = e > 0.f ? e : 0.2f * e; m = fmaxf(m, e);
  }
  float den = 0.f;
  for (int i = s0; i < s1; i++){
    float e = el[csr[i]] + erv; e = e > 0.f ? e : 0.2f * e; den += expf(e - m);
  }
  float inv = 1.f / den;
  for (int i = s0; i < s1; i++){
    float e = el[csr[i]] + erv; e = e > 0.f ? e : 0.2f * e; a[i] = expf(e - m) * inv;
  }
}

// ---------------- FUSED layer 1: gather x0 -> x1 tile -> el2/er2 + y1=W2*x1 (24b) ----------------
__global__ __launch_bounds__(512, 4) void l1_fused(
    const float* __restrict__ x0, const float* __restrict__ W1, const float* __restrict__ bias1,
    const float* __restrict__ a1, const float* __restrict__ W2,
    const float* __restrict__ V2L, const float* __restrict__ V2R,
    const int* __restrict__ rp, const int* __restrict__ csr,
    ushort_t* __restrict__ y1hi, unsigned char* __restrict__ y1lo,
    float* __restrict__ el2, float* __restrict__ er2){
  __shared__ float agg[4][B1][129];     // 33024B
  __shared__ float Wbuf[32 * 129];      // 16512B (holds [32][129] or [16][257])
  __shared__ float x1s[B1][257];        // 16448B
  __shared__ float als[EC1][4];
  __shared__ int   ssrc[EC1];
  __shared__ int   rpc[B1 + 1];
  int t = threadIdx.x;
  int nb0 = blockIdx.x * B1;
  if (t <= B1) rpc[t] = rp[nb0 + t];
  __syncthreads();
  int e0 = rpc[0], eN = rpc[B1];
  int c = t & 127, g = t >> 7;          // col 0..127, dst-group 0..3

  float accr[4][4];                     // [dd][head]
  #pragma unroll
  for (int dd = 0; dd < 4; dd++)
    #pragma unroll
    for (int h = 0; h < 4; h++) accr[dd][h] = 0.f;

  for (int c0 = e0; c0 < eN; c0 += EC1){
    int ce = min(EC1, eN - c0);
    for (int i = t; i < ce; i += 512){
      ssrc[i] = csr[c0 + i];
      float4 av = *reinterpret_cast<const float4*>(a1 + (size_t)(c0 + i) * 4);
      als[i][0] = av.x; als[i][1] = av.y; als[i][2] = av.z; als[i][3] = av.w;
    }
    __syncthreads();
    #pragma unroll
    for (int dd = 0; dd < 4; dd++){
      int d = g + dd * 4;
      int lo = max(rpc[d], c0) - c0;
      int hi = min(rpc[d + 1], c0 + ce) - c0;
      for (int i = lo; i < hi; i++){
        float xv = x0[(size_t)ssrc[i] * 128 + c];
        accr[dd][0] += als[i][0] * xv;
        accr[dd][1] += als[i][1] * xv;
        accr[dd][2] += als[i][2] * xv;
        accr[dd][3] += als[i][3] * xv;
      }
    }
    __syncthreads();
  }
  #pragma unroll
  for (int dd = 0; dd < 4; dd++){
    int d = g + dd * 4;
    agg[0][d][c] = accr[dd][0];
    agg[1][d][c] = accr[dd][1];
    agg[2][d][c] = accr[dd][2];
    agg[3][d][c] = accr[dd][3];
  }
  __syncthreads();

  // x1 = selu(W1 . agg + b1): 8 chunks of 32 output rows (head = ch>>1)
  for (int ch = 0; ch < 8; ch++){
    for (int i = t; i < 32 * 32; i += 512){
      int r = i >> 5, k4 = i & 31;
      float4 w = *reinterpret_cast<const float4*>(W1 + (size_t)(ch * 32 + r) * 128 + k4 * 4);
      Wbuf[r * 129 + k4 * 4 + 0] = w.x; Wbuf[r * 129 + k4 * 4 + 1] = w.y;
      Wbuf[r * 129 + k4 * 4 + 2] = w.z; Wbuf[r * 129 + k4 * 4 + 3] = w.w;
    }
    __syncthreads();
    {
      int m = t & 31, d = t >> 5;
      int h = ch >> 1;
      float s = 0.f;
      #pragma unroll 4
      for (int k = 0; k < 128; k++) s += Wbuf[m * 129 + k] * agg[h][d][k];
      int col = ch * 32 + m;
      x1s[d][col] = selu_f(s + bias1[col]);
    }
    __syncthreads();
  }

  // el2/er2: 128 tasks (16d x 4h x LR) x 4 threads, interleaved k
  {
    int task = t >> 2, q = t & 3;
    int d = task & 15, hq = (task >> 4) & 3, lr = task >> 6;
    const float* V = lr ? V2R : V2L;
    float p = 0.f;
    for (int kk = 0; kk < 64; kk++){
      int k = q + kk * 4;
      p += V[hq * 256 + k] * x1s[d][k];
    }
    p += __shfl_xor(p, 1);
    p += __shfl_xor(p, 2);
    if (q == 0){
      if (lr) er2[(size_t)(nb0 + d) * 4 + hq] = p;
      else    el2[(size_t)(nb0 + d) * 4 + hq] = p;
    }
  }

  // y1 = W2 . x1 (no activation), 24-bit split store: 16 chunks of 16 rows
  for (int ch = 0; ch < 16; ch++){
    __syncthreads();
    for (int i = t; i < 16 * 64; i += 512){
      int r = i >> 6, k4 = i & 63;
      float4 w = *reinterpret_cast<const float4*>(W2 + (size_t)(ch * 16 + r) * 256 + k4 * 4);
      Wbuf[r * 257 + k4 * 4 + 0] = w.x; Wbuf[r * 257 + k4 * 4 + 1] = w.y;
      Wbuf[r * 257 + k4 * 4 + 2] = w.z; Wbuf[r * 257 + k4 * 4 + 3] = w.w;
    }
    __syncthreads();
    if (t < 256){
      int m = t & 15, d = t >> 4;
      float s = 0.f;
      #pragma unroll 4
      for (int k = 0; k < 256; k++) s += Wbuf[m * 257 + k] * x1s[d][k];
      int col = ch * 16 + m;
      unsigned int u = __float_as_uint(s);
      y1hi[(size_t)(nb0 + d) * 256 + col] = (ushort_t)(u >> 16);
      y1lo[(size_t)(nb0 + d) * 256 + col] = (unsigned char)(u >> 8);
    }
  }
}

// ---------------- layer-2 gather: x2 = selu(sum a2*y1 + b2) -> el3/er3 + feat3=W3*x2 ----------------
__global__ __launch_bounds__(256, 4) void l2_gather(
    const ushort_t* __restrict__ y1hi, const unsigned char* __restrict__ y1lo,
    const float* __restrict__ bias2, const float* __restrict__ a2,
    const float* __restrict__ W3,
    const float* __restrict__ V3L, const float* __restrict__ V3R,
    const int* __restrict__ rp, const int* __restrict__ csr,
    float* __restrict__ feat3, float* __restrict__ el3, float* __restrict__ er3){
  __shared__ float x2s[B2G][257];       // 16448B
  __shared__ float W3c[16 * 257];       // 16448B
  __shared__ float als[EC2][4];
  __shared__ int   ssrc[EC2];
  __shared__ int   rpc[B2G + 1];
  int t = threadIdx.x;
  int nb0 = blockIdx.x * B2G;
  if (t <= B2G) rpc[t] = rp[nb0 + t];
  __syncthreads();
  int e0 = rpc[0], eN = rpc[B2G];
  int c = t;                            // column 0..255
  int h = c >> 6;

  float acc[B2G];
  #pragma unroll
  for (int d = 0; d < B2G; d++) acc[d] = 0.f;

  for (int c0 = e0; c0 < eN; c0 += EC2){
    int ce = min(EC2, eN - c0);
    for (int i = t; i < ce; i += 256){
      ssrc[i] = csr[c0 + i];
      float4 av = *reinterpret_cast<const float4*>(a2 + (size_t)(c0 + i) * 4);
      als[i][0] = av.x; als[i][1] = av.y; als[i][2] = av.z; als[i][3] = av.w;
    }
    __syncthreads();
    #pragma unroll
    for (int d = 0; d < B2G; d++){
      int lo = max(rpc[d], c0) - c0;
      int hi = min(rpc[d + 1], c0 + ce) - c0;
      for (int i = lo; i < hi; i++){
        size_t s = (size_t)ssrc[i] * 256 + c;
        unsigned int u = ((unsigned int)y1hi[s] << 16) | ((unsigned int)y1lo[s] << 8);
        acc[d] += als[i][h] * __uint_as_float(u);
      }
    }
    __syncthreads();
  }
  {
    float b = bias2[c];
    #pragma unroll
    for (int d = 0; d < B2G; d++) x2s[d][c] = selu_f(acc[d] + b);
  }
  __syncthreads();

  // el3/er3: 32 tasks x 8 threads, interleaved k
  {
    int task = t >> 3, j = t & 7;
    int d = task & 15, lr = task >> 4;
    const float* V = lr ? V3R : V3L;
    float p = 0.f;
    for (int kk = 0; kk < 32; kk++){
      int k = j + kk * 8;
      p += V[k] * x2s[d][k];
    }
    p += __shfl_xor(p, 1); p += __shfl_xor(p, 2); p += __shfl_xor(p, 4);
    if (j == 0){ if (lr) er3[nb0 + d] = p; else el3[nb0 + d] = p; }
  }

  // feat3 = W3 . x2 : 4 chunks of 16 rows
  for (int ch = 0; ch < 4; ch++){
    __syncthreads();
    for (int i = t; i < 16 * 64; i += 256){
      int r = i >> 6, k4 = i & 63;
      float4 w = *reinterpret_cast<const float4*>(W3 + (size_t)(ch * 16 + r) * 256 + k4 * 4);
      W3c[r * 257 + k4 * 4 + 0] = w.x; W3c[r * 257 + k4 * 4 + 1] = w.y;
      W3c[r * 257 + k4 * 4 + 2] = w.z; W3c[r * 257 + k4 * 4 + 3] = w.w;
    }
    __syncthreads();
    {
      int r = t & 15, d = t >> 4;
      float s = 0.f;
      #pragma unroll 4
      for (int k = 0; k < 256; k++) s += W3c[r * 257 + k] * x2s[d][k];
      feat3[(size_t)(nb0 + d) * 64 + ch * 16 + r] = s;
    }
  }
}

// ---------------- layer-3 aggregation with precomputed alpha ----------------
__global__ __launch_bounds__(256) void gat_agg3(const float* __restrict__ feat, const float* __restrict__ a3,
                                                const int* __restrict__ rp, const int* __restrict__ csr,
                                                const float* __restrict__ bias,
                                                float* __restrict__ out, int n){
  int node = blockIdx.x * 4 + (threadIdx.x >> 6);
  int t = threadIdx.x & 63;
  if (node >= n) return;
  int s0 = rp[node], s1 = rp[node + 1];
  float acc = 0.f;
  for (int i = s0; i < s1; i++){
    acc += a3[i] * feat[(size_t)csr[i] * 64 + t];
  }
  out[(size_t)node * 64 + t] = selu_f(acc + bias[t]);
}

// ---------------- readout ----------------
__global__ void readout_kernel(const float* __restrict__ x3, const float* __restrict__ score_w,
                               const float* __restrict__ score_b, const int* __restrict__ gids,
                               float* __restrict__ num, float* __restrict__ den, int n){
  int node = blockIdx.x * 4 + (threadIdx.x >> 6);
  int lane = threadIdx.x & 63;
  if (node >= n) return;
  float xv = x3[(size_t)node * 64 + lane];
  float p = xv * score_w[lane];
  #pragma unroll
  for (int off = 32; off; off >>= 1) p += __shfl_xor(p, off);
  float w = 1.f / (1.f + expf(-(p + score_b[0])));
  int g = gids[node];
  atomicAdd(&num[(size_t)g * 64 + lane], w * xv);
  if (lane == 0) atomicAdd(&den[g], w);
}

// ---------------- final MLP ----------------
__global__ __launch_bounds__(128) void mlp_kernel(
    const float* __restrict__ num, const float* __restrict__ den,
    const float* __restrict__ fg,
    const float* __restrict__ w1, const float* __restrict__ b1,
    const float* __restrict__ w2, const float* __restrict__ b2,
    const float* __restrict__ w3, const float* __restrict__ b3,
    float* __restrict__ out, int G){
  __shared__ float z[80];
  __shared__ float h1[128];
  __shared__ float h2[64];
  int t = threadIdx.x;
  for (int g = blockIdx.x; g < G; g += gridDim.x){
    if (t < 64){
      float d = den[g];
      d = (d == 0.f) ? 1.f : d;
      z[t] = num[(size_t)g * 64 + t] / d;
    } else if (t < 80){
      z[t] = fg[(size_t)g * 16 + (t - 64)];
    }
    __syncthreads();
    {
      float a = b1[t];
      for (int k = 0; k < 80; k++) a += z[k] * w1[t * 80 + k];
      h1[t] = selu_f(a);
    }
    __syncthreads();
    if (t < 64){
      float a = b2[t];
      for (int k = 0; k < 128; k++) a += h1[k] * w2[t * 128 + k];
      h2[t] = selu_f(a);
    }
    __syncthreads();
    if (t < 64){
      float p = h2[t] * w3[t];
      #pragma unroll
      for (int off = 32; off; off >>= 1) p += __shfl_down(p, off);
      if (t == 0) out[g] = p + b3[0];
    }
    __syncthreads();
  }
}

// ---------------- launch ----------------
extern "C" void kernel_launch(void* const* d_in, const int* in_sizes, int n_in,
                              void* d_out, int out_size, void* d_ws, size_t ws_size,
                              hipStream_t stream) {
  const float* feats_node  = (const float*)d_in[0];
  const float* feats_graph = (const float*)d_in[1];
  const int*   src         = (const int*)d_in[2];
  const int*   dst         = (const int*)d_in[3];
  const int*   gids        = (const int*)d_in[4];
  const float* fc1_w   = (const float*)d_in[5];
  const float* attn_l1 = (const float*)d_in[6];
  const float* attn_r1 = (const float*)d_in[7];
  const float* bias1   = (const float*)d_in[8];
  const float* fc2_w   = (const float*)d_in[9];
  const float* attn_l2 = (const float*)d_in[10];
  const float* attn_r2 = (const float*)d_in[11];
  const float* bias2   = (const float*)d_in[12];
  const float* fc3_w   = (const float*)d_in[13];
  const float* attn_l3 = (const float*)d_in[14];
  const float* attn_r3 = (const float*)d_in[15];
  const float* bias3   = (const float*)d_in[16];
  const float* score_w = (const float*)d_in[17];
  const float* score_b = (const float*)d_in[18];
  const float* mlp_w1  = (const float*)d_in[19];
  const float* mlp_b1  = (const float*)d_in[20];
  const float* mlp_w2  = (const float*)d_in[21];
  const float* mlp_b2  = (const float*)d_in[22];
  const float* mlp_w3  = (const float*)d_in[23];
  const float* mlp_b3  = (const float*)d_in[24];
  float* out = (float*)d_out;

  char* ws = (char*)d_ws;
  size_t off = 0;
  auto alloc = [&](size_t bytes) -> void* {
    void* p = ws + off;
    off += (bytes + 255) / 256 * 256;
    return p;
  };
  int*   deg   = (int*)alloc((size_t)N_NODES * 4);
  int*   fil   = (int*)alloc((size_t)N_NODES * 4);
  int*   rp    = (int*)alloc((size_t)(N_NODES + 1) * 4);
  int*   bs    = (int*)alloc(256 * 4);
  int*   csr   = (int*)alloc((size_t)N_EDGES * 4);
  float* elbuf = (float*)alloc((size_t)N_NODES * 4 * 4);
  float* erbuf = (float*)alloc((size_t)N_NODES * 4 * 4);
  float* V1L   = (float*)alloc(512 * 4);
  float* V1R   = (float*)alloc(512 * 4);
  float* V2L   = (float*)alloc(1024 * 4);
  float* V2R   = (float*)alloc(1024 * 4);
  float* V3L   = (float*)alloc(256 * 4);
  float* V3R   = (float*)alloc(256 * 4);
  float* num   = (float*)alloc((size_t)N_GRAPHS * 64 * 4);
  float* den   = (float*)alloc((size_t)N_GRAPHS * 4);
  float* A     = (float*)alloc((size_t)N_EDGES * 4 * 4);     // alpha buffer, reused per layer
  float* feat3 = (float*)alloc((size_t)N_NODES * 64 * 4);
  ushort_t*      y1hi = (ushort_t*)alloc((size_t)N_NODES * 256 * 2);
  unsigned char* y1lo = (unsigned char*)alloc((size_t)N_NODES * 256);
  float* x3 = (float*)y1hi;  // overlay: y1 dead after l2_gather

  zero_i32<<<(N_NODES + 255) / 256, 256, 0, stream>>>(deg, N_NODES);
  zero_i32<<<(N_NODES + 255) / 256, 256, 0, stream>>>(fil, N_NODES);
  zero_i32<<<(N_GRAPHS * 64 + 255) / 256, 256, 0, stream>>>((int*)num, N_GRAPHS * 64);
  zero_i32<<<(N_GRAPHS + 255) / 256, 256, 0, stream>>>((int*)den, N_GRAPHS);

  deg_kernel<<<(N_EDGES + 255) / 256, 256, 0, stream>>>(dst, deg, N_EDGES);
  scan1<<<196, 256, 0, stream>>>(deg, rp, bs, N_NODES);
  scan2<<<1, 256, 0, stream>>>(bs, 196);
  scan3<<<(N_NODES + 255) / 256, 256, 0, stream>>>(rp, bs, N_NODES, N_EDGES);
  fill_csr<<<(N_EDGES + 255) / 256, 256, 0, stream>>>(src, dst, rp, fil, csr, N_EDGES);

  compute_v<<<7, 256, 0, stream>>>(fc1_w, attn_l1, attn_r1, fc2_w, attn_l2, attn_r2,
                                   fc3_w, attn_l3, attn_r3, V1L, V1R, V2L, V2R, V3L, V3R);
  el_er1<<<N_NODES / 4, 256, 0, stream>>>(feats_node, V1L, V1R, elbuf, erbuf, N_NODES);

  // layer 1
  alpha_h4<<<(N_NODES + 255) / 256, 256, 0, stream>>>(elbuf, erbuf, rp, csr, A, N_NODES);
  l1_fused<<<N_NODES / B1, 512, 0, stream>>>(feats_node, fc1_w, bias1, A, fc2_w,
                                             V2L, V2R, rp, csr, y1hi, y1lo, elbuf, erbuf);
  // layer 2
  alpha_h4<<<(N_NODES + 255) / 256, 256, 0, stream>>>(elbuf, erbuf, rp, csr, A, N_NODES);
  l2_gather<<<N_NODES / B2G, 256, 0, stream>>>(y1hi, y1lo, bias2, A, fc3_w,
                                               V3L, V3R, rp, csr, feat3, elbuf, erbuf);
  // layer 3
  alpha_h1<<<(N_NODES + 255) / 256, 256, 0, stream>>>(elbuf, erbuf, rp, csr, A, N_NODES);
  gat_agg3<<<N_NODES / 4, 256, 0, stream>>>(feat3, A, rp, csr, bias3, x3, N_NODES);

  readout_kernel<<<N_NODES / 4, 256, 0, stream>>>(x3, score_w, score_b, gids, num, den, N_NODES);
  mlp_kernel<<<256, 128, 0, stream>>>(num, den, feats_graph,
                                      mlp_w1, mlp_b1, mlp_w2, mlp_b2, mlp_w3, mlp_b3,
                                      out, N_GRAPHS);
}

// Round 6
// 2765.671 us; speedup vs baseline: 6.1788x; 1.4450x over previous
//
#include <hip/hip_runtime.h>
#include <math.h>

#define N_NODES 200000
#define N_EDGES 800000
#define N_GRAPHS 8192
#define B1 16       // dst nodes per block, layer-1 fused
#define B2 8        // dst nodes per block, layer-2 fused
#define EC 128      // edge chunk

typedef unsigned short ushort_t;

__device__ __forceinline__ float selu_f(float x){
  const float alpha = 1.6732632423543772f;
  const float lam   = 1.0507009873554805f;
  return x > 0.f ? lam * x : lam * alpha * (expf(x) - 1.f);
}

// ---------------- utility ----------------
__global__ void zero_i32(int* p, int n){
  int i = blockIdx.x * 256 + threadIdx.x;
  if (i < n) p[i] = 0;
}

// ---------------- CSR build ----------------
__global__ void deg_kernel(const int* __restrict__ dst, int* __restrict__ deg, int E){
  int e = blockIdx.x * 256 + threadIdx.x;
  if (e < E) atomicAdd(&deg[dst[e]], 1);
}

__global__ void scan1(const int* __restrict__ deg, int* __restrict__ rp, int* __restrict__ bs, int n){
  __shared__ int sh[256];
  int t = threadIdx.x;
  int base = blockIdx.x * 1024;
  int v[4]; int s = 0;
  #pragma unroll
  for (int i = 0; i < 4; i++){
    int idx = base + t * 4 + i;
    v[i] = (idx < n) ? deg[idx] : 0;
    s += v[i];
  }
  sh[t] = s; __syncthreads();
  for (int off = 1; off < 256; off <<= 1){
    int x = (t >= off) ? sh[t - off] : 0;
    __syncthreads();
    sh[t] += x;
    __syncthreads();
  }
  int run = (t == 0) ? 0 : sh[t - 1];
  #pragma unroll
  for (int i = 0; i < 4; i++){
    int idx = base + t * 4 + i;
    if (idx < n) rp[idx] = run;
    run += v[i];
  }
  if (t == 255) bs[blockIdx.x] = sh[255];
}

__global__ void scan2(int* bs, int nb){
  __shared__ int sh[256];
  int t = threadIdx.x;
  sh[t] = (t < nb) ? bs[t] : 0; __syncthreads();
  for (int off = 1; off < 256; off <<= 1){
    int x = (t >= off) ? sh[t - off] : 0;
    __syncthreads();
    sh[t] += x;
    __syncthreads();
  }
  int excl = (t == 0) ? 0 : sh[t - 1];
  if (t < nb) bs[t] = excl;
}

__global__ void scan3(int* rp, const int* __restrict__ bs, int n, int total){
  int i = blockIdx.x * 256 + threadIdx.x;
  if (i < n) rp[i] += bs[i >> 10];
  if (i == 0) rp[n] = total;
}

__global__ void fill_csr(const int* __restrict__ src, const int* __restrict__ dst,
                         const int* __restrict__ rp, int* __restrict__ fil,
                         int* __restrict__ csr, int E){
  int e = blockIdx.x * 256 + threadIdx.x;
  if (e < E){
    int d = dst[e];
    int p = atomicAdd(&fil[d], 1);
    csr[rp[d] + p] = src[e];
  }
}

// ---------------- weight transposes: Wt[k][m] = W[m][k] ----------------
__global__ void wt_kernel(const float* __restrict__ W1, const float* __restrict__ W2,
                          const float* __restrict__ W3,
                          float* __restrict__ W1t, float* __restrict__ W2t,
                          float* __restrict__ W3t){
  int i = blockIdx.x * 256 + threadIdx.x;
  if (i < 32768){
    int k = i >> 8, m = i & 255;
    W1t[i] = W1[(size_t)m * 128 + k];
  } else if (i < 32768 + 65536){
    int j = i - 32768;
    int k = j >> 8, m = j & 255;
    W2t[j] = W2[(size_t)m * 256 + k];
  } else if (i < 32768 + 65536 + 16384){
    int j = i - 32768 - 65536;
    int k = j >> 6, c = j & 63;
    W3t[j] = W3[(size_t)c * 256 + k];
  }
}

// ---------------- V = attn^T W precompute ----------------
__global__ void compute_v(const float* __restrict__ W1, const float* __restrict__ al1, const float* __restrict__ ar1,
                          const float* __restrict__ W2, const float* __restrict__ al2, const float* __restrict__ ar2,
                          const float* __restrict__ W3, const float* __restrict__ al3, const float* __restrict__ ar3,
                          float* __restrict__ V1L, float* __restrict__ V1R,
                          float* __restrict__ V2L, float* __restrict__ V2R,
                          float* __restrict__ V3L, float* __restrict__ V3R){
  int i = blockIdx.x * 256 + threadIdx.x;
  if (i < 512){
    int h = i >> 7, k = i & 127;
    float sl = 0.f, sr = 0.f;
    for (int dd = 0; dd < 64; dd++){
      float w = W1[(size_t)(h * 64 + dd) * 128 + k];
      sl += al1[h * 64 + dd] * w;
      sr += ar1[h * 64 + dd] * w;
    }
    V1L[i] = sl; V1R[i] = sr;
  } else if (i < 1536){
    int j = i - 512;
    int h = j >> 8, k = j & 255;
    float sl = 0.f, sr = 0.f;
    for (int dd = 0; dd < 64; dd++){
      float w = W2[(size_t)(h * 64 + dd) * 256 + k];
      sl += al2[h * 64 + dd] * w;
      sr += ar2[h * 64 + dd] * w;
    }
    V2L[j] = sl; V2R[j] = sr;
  } else if (i < 1792){
    int k = i - 1536;
    float sl = 0.f, sr = 0.f;
    for (int dd = 0; dd < 64; dd++){
      float w = W3[(size_t)dd * 256 + k];
      sl += al3[dd] * w;
      sr += ar3[dd] * w;
    }
    V3L[k] = sl; V3R[k] = sr;
  }
}

// ---------------- el/er for layer 1 ----------------
__global__ __launch_bounds__(256) void el_er1(const float* __restrict__ x0,
                                              const float* __restrict__ V1L, const float* __restrict__ V1R,
                                              float* __restrict__ el1, float* __restrict__ er1, int n){
  __shared__ float vl[512], vr[512];
  int t = threadIdx.x;
  for (int i = t; i < 512; i += 256){ vl[i] = V1L[i]; vr[i] = V1R[i]; }
  __syncthreads();
  int node = blockIdx.x * 4 + (t >> 6);
  int l = t & 63;
  if (node >= n) return;
  float xa = x0[(size_t)node * 128 + l];
  float xb = x0[(size_t)node * 128 + 64 + l];
  #pragma unroll
  for (int h = 0; h < 4; h++){
    float pl = xa * vl[h * 128 + l] + xb * vl[h * 128 + 64 + l];
    float pr = xa * vr[h * 128 + l] + xb * vr[h * 128 + 64 + l];
    #pragma unroll
    for (int off = 32; off; off >>= 1){ pl += __shfl_xor(pl, off); pr += __shfl_xor(pr, off); }
    if (l == 0){ el1[(size_t)node * 4 + h] = pl; er1[(size_t)node * 4 + h] = pr; }
  }
}

// ---------------- alpha kernels ----------------
__global__ __launch_bounds__(256) void alpha_h4(const float* __restrict__ el, const float* __restrict__ er,
                                                const int* __restrict__ rp, const int* __restrict__ csr,
                                                float* __restrict__ a, int n){
  int node = blockIdx.x * 256 + threadIdx.x;
  if (node >= n) return;
  int s0 = rp[node], s1 = rp[node + 1];
  if (s0 >= s1) return;
  float4 erv = *reinterpret_cast<const float4*>(er + (size_t)node * 4);
  float m0 = -1e30f, m1 = -1e30f, m2 = -1e30f, m3 = -1e30f;
  for (int i = s0; i < s1; i++){
    float4 e = *reinterpret_cast<const float4*>(el + (size_t)csr[i] * 4);
    float e0 = e.x + erv.x; e0 = e0 > 0.f ? e0 : 0.2f * e0; m0 = fmaxf(m0, e0);
    float e1 = e.y + erv.y; e1 = e1 > 0.f ? e1 : 0.2f * e1; m1 = fmaxf(m1, e1);
    float e2 = e.z + erv.z; e2 = e2 > 0.f ? e2 : 0.2f * e2; m2 = fmaxf(m2, e2);
    float e3 = e.w + erv.w; e3 = e3 > 0.f ? e3 : 0.2f * e3; m3 = fmaxf(m3, e3);
  }
  float d0 = 0.f, d1 = 0.f, d2 = 0.f, d3 = 0.f;
  for (int i = s0; i < s1; i++){
    float4 e = *reinterpret_cast<const float4*>(el + (size_t)csr[i] * 4);
    float e0 = e.x + erv.x; e0 = e0 > 0.f ? e0 : 0.2f * e0; d0 += expf(e0 - m0);
    float e1 = e.y + erv.y; e1 = e1 > 0.f ? e1 : 0.2f * e1; d1 += expf(e1 - m1);
    float e2 = e.z + erv.z; e2 = e2 > 0.f ? e2 : 0.2f * e2; d2 += expf(e2 - m2);
    float e3 = e.w + erv.w; e3 = e3 > 0.f ? e3 : 0.2f * e3; d3 += expf(e3 - m3);
  }
  d0 = 1.f / d0; d1 = 1.f / d1; d2 = 1.f / d2; d3 = 1.f / d3;
  for (int i = s0; i < s1; i++){
    float4 e = *reinterpret_cast<const float4*>(el + (size_t)csr[i] * 4);
    float4 o;
    float e0 = e.x + erv.x; e0 = e0 > 0.f ? e0 : 0.2f * e0; o.x = expf(e0 - m0) * d0;
    float e1 = e.y + erv.y; e1 = e1 > 0.f ? e1 : 0.2f * e1; o.y = expf(e1 - m1) * d1;
    float e2 = e.z + erv.z; e2 = e2 > 0.f ? e2 : 0.2f * e2; o.z = expf(e2 - m2) * d2;
    float e3 = e.w + erv.w; e3 = e3 > 0.f ? e3 : 0.2f * e3; o.w = expf(e3 - m3) * d3;
    *reinterpret_cast<float4*>(a + (size_t)i * 4) = o;
  }
}

__global__ __launch_bounds__(256) void alpha_h1(const float* __restrict__ el, const float* __restrict__ er,
                                                const int* __restrict__ rp, const int* __restrict__ csr,
                                                float* __restrict__ a, int n){
  int node = blockIdx.x * 256 + threadIdx.x;
  if (node >= n) return;
  int s0 = rp[node], s1 = rp[node + 1];
  if (s0 >= s1) return;
  float erv = er[node];
  float m = -1e30f;
  for (int i = s0; i < s1; i++){
    float e = el[csr[i]] + erv; e = e > 0.f ? e : 0.2f * e; m = fmaxf(m, e);
  }
  float den = 0.f;
  for (int i = s0; i < s1; i++){
    float e = el[csr[i]] + erv; e = e > 0.f ? e : 0.2f * e; den += expf(e - m);
  }
  float inv = 1.f / den;
  for (int i = s0; i < s1; i++){
    float e = el[csr[i]] + erv; e = e > 0.f ? e : 0.2f * e; a[i] = expf(e - m) * inv;
  }
}

// ---------------- FUSED layer 1: gather x0 -> GEMM W1 -> x1(24b) + el2/er2 ----------------
__global__ __launch_bounds__(512, 2) void l1_fused(
    const float* __restrict__ x0, const float* __restrict__ W1t, const float* __restrict__ bias1,
    const float* __restrict__ a1,
    const float* __restrict__ V2L, const float* __restrict__ V2R,
    const int* __restrict__ rp, const int* __restrict__ csr,
    ushort_t* __restrict__ x1hi, unsigned char* __restrict__ x1lo,
    float* __restrict__ el2, float* __restrict__ er2){
  __shared__ float  aggT[4][129][20];   // [h][k][d] 41.3 KB, h-stride quad-spread, d-contig
  __shared__ float  x1s[16][260];       // 16.6 KB
  __shared__ float4 als4[EC];
  __shared__ int    ssrc[EC];
  __shared__ int    rpc[B1 + 1];
  int t = threadIdx.x;
  int nb0 = blockIdx.x * B1;
  if (t <= B1) rpc[t] = rp[nb0 + t];
  __syncthreads();
  int e0 = rpc[0], eN = rpc[B1];

  // ---- gather phase: accumulate in registers ----
  {
    int c = t & 127, g = t >> 7;        // k-col 0..127, dst-group 0..3
    float accr[4][4] = {{0.f}};         // [dd][head]
    for (int c0 = e0; c0 < eN; c0 += EC){
      int ce = min(EC, eN - c0);
      for (int i = t; i < ce; i += 512){
        ssrc[i] = csr[c0 + i];
        als4[i] = *reinterpret_cast<const float4*>(a1 + (size_t)(c0 + i) * 4);
      }
      __syncthreads();
      #pragma unroll
      for (int dd = 0; dd < 4; dd++){
        int d = g + dd * 4;
        int lo = max(rpc[d], c0) - c0;
        int hi = min(rpc[d + 1], c0 + ce) - c0;
        for (int i = lo; i < hi; i++){
          float xv = x0[(size_t)ssrc[i] * 128 + c];
          float4 av = als4[i];
          accr[dd][0] += av.x * xv;
          accr[dd][1] += av.y * xv;
          accr[dd][2] += av.z * xv;
          accr[dd][3] += av.w * xv;
        }
      }
      __syncthreads();
    }
    #pragma unroll
    for (int dd = 0; dd < 4; dd++){
      int d = g + dd * 4;
      aggT[0][c][d] = accr[dd][0];
      aggT[1][c][d] = accr[dd][1];
      aggT[2][c][d] = accr[dd][2];
      aggT[3][c][d] = accr[dd][3];
    }
  }
  __syncthreads();

  // ---- GEMM1: x1[d][m] = selu(sum_k W1[m][k]*agg[h(m)][k][d] + b1), 4x4 reg tile ----
  if (t < 256){
    int mt = t & 63, dt = t >> 6;
    int m0 = mt * 4, d0 = dt * 4, h = mt >> 4;
    float acc[4][4] = {{0.f}};
    #pragma unroll 4
    for (int k = 0; k < 128; k++){
      float4 w = *reinterpret_cast<const float4*>(W1t + (size_t)k * 256 + m0);
      float4 a = *reinterpret_cast<const float4*>(&aggT[h][k][d0]);
      acc[0][0] += a.x * w.x; acc[0][1] += a.x * w.y; acc[0][2] += a.x * w.z; acc[0][3] += a.x * w.w;
      acc[1][0] += a.y * w.x; acc[1][1] += a.y * w.y; acc[1][2] += a.y * w.z; acc[1][3] += a.y * w.w;
      acc[2][0] += a.z * w.x; acc[2][1] += a.z * w.y; acc[2][2] += a.z * w.z; acc[2][3] += a.z * w.w;
      acc[3][0] += a.w * w.x; acc[3][1] += a.w * w.y; acc[3][2] += a.w * w.z; acc[3][3] += a.w * w.w;
    }
    float4 b = *reinterpret_cast<const float4*>(bias1 + m0);
    #pragma unroll
    for (int i = 0; i < 4; i++){
      float4 v;
      v.x = selu_f(acc[i][0] + b.x);
      v.y = selu_f(acc[i][1] + b.y);
      v.z = selu_f(acc[i][2] + b.z);
      v.w = selu_f(acc[i][3] + b.w);
      *reinterpret_cast<float4*>(&x1s[d0 + i][m0]) = v;
      unsigned int ux = __float_as_uint(v.x), uy = __float_as_uint(v.y);
      unsigned int uz = __float_as_uint(v.z), uw = __float_as_uint(v.w);
      ushort4 h4; uchar4 l4;
      h4.x = (ushort_t)(ux >> 16); h4.y = (ushort_t)(uy >> 16);
      h4.z = (ushort_t)(uz >> 16); h4.w = (ushort_t)(uw >> 16);
      l4.x = (unsigned char)(ux >> 8); l4.y = (unsigned char)(uy >> 8);
      l4.z = (unsigned char)(uz >> 8); l4.w = (unsigned char)(uw >> 8);
      size_t base = (size_t)(nb0 + d0 + i) * 256 + m0;
      *reinterpret_cast<ushort4*>(x1hi + base) = h4;
      *reinterpret_cast<uchar4*>(x1lo + base) = l4;
    }
  }
  __syncthreads();

  // ---- el2/er2 from fp32 x1 tile ----
  if (t < 128){
    int d = t & 15, hq = (t >> 4) & 3, lr = t >> 6;
    const float* V = lr ? V2R : V2L;
    float p = 0.f;
    for (int k = 0; k < 256; k++) p += V[hq * 256 + k] * x1s[d][k];
    if (lr) er2[(size_t)(nb0 + d) * 4 + hq] = p;
    else    el2[(size_t)(nb0 + d) * 4 + hq] = p;
  }
}

// ---------------- FUSED layer 2: gather x1(24b) -> GEMM W2 -> x2 -> el3/er3 + feat3 ----------------
__global__ __launch_bounds__(512, 2) void l2_fused(
    const ushort_t* __restrict__ x1hi, const unsigned char* __restrict__ x1lo,
    const float* __restrict__ W2t, const float* __restrict__ bias2,
    const float* __restrict__ a2, const float* __restrict__ W3t,
    const float* __restrict__ V3L, const float* __restrict__ V3R,
    const int* __restrict__ rp, const int* __restrict__ csr,
    float* __restrict__ feat3, float* __restrict__ el3, float* __restrict__ er3){
  __shared__ float  aggT[4][257][12];   // [h][k][d] 49.3 KB
  __shared__ float  x2s[8][260];        // 8.3 KB
  __shared__ float4 als4[EC];
  __shared__ int    ssrc[EC];
  __shared__ int    rpc[B2 + 1];
  int t = threadIdx.x;
  int nb0 = blockIdx.x * B2;
  if (t <= B2) rpc[t] = rp[nb0 + t];
  __syncthreads();
  int e0 = rpc[0], eN = rpc[B2];

  // ---- gather phase ----
  {
    int c = t & 255, g = t >> 8;        // k-col 0..255, dst-group 0..1
    float accr[4][4] = {{0.f}};         // [dd][head]
    for (int c0 = e0; c0 < eN; c0 += EC){
      int ce = min(EC, eN - c0);
      for (int i = t; i < ce; i += 512){
        ssrc[i] = csr[c0 + i];
        als4[i] = *reinterpret_cast<const float4*>(a2 + (size_t)(c0 + i) * 4);
      }
      __syncthreads();
      #pragma unroll
      for (int dd = 0; dd < 4; dd++){
        int d = g * 4 + dd;
        int lo = max(rpc[d], c0) - c0;
        int hi = min(rpc[d + 1], c0 + ce) - c0;
        for (int i = lo; i < hi; i++){
          size_t s = (size_t)ssrc[i] * 256 + c;
          unsigned int u = ((unsigned int)x1hi[s] << 16) | ((unsigned int)x1lo[s] << 8);
          float xv = __uint_as_float(u);
          float4 av = als4[i];
          accr[dd][0] += av.x * xv;
          accr[dd][1] += av.y * xv;
          accr[dd][2] += av.z * xv;
          accr[dd][3] += av.w * xv;
        }
      }
      __syncthreads();
    }
    #pragma unroll
    for (int dd = 0; dd < 4; dd++){
      int d = g * 4 + dd;
      aggT[0][c][d] = accr[dd][0];
      aggT[1][c][d] = accr[dd][1];
      aggT[2][c][d] = accr[dd][2];
      aggT[3][c][d] = accr[dd][3];
    }
  }
  __syncthreads();

  // ---- GEMM2: x2[d][m] = selu(sum_k W2[m][k]*agg[h(m)][k][d] + b2), 4x4 tile ----
  if (t < 128){
    int mt = t & 63, dt = t >> 6;
    int m0 = mt * 4, d0 = dt * 4, h = mt >> 4;
    float acc[4][4] = {{0.f}};
    #pragma unroll 4
    for (int k = 0; k < 256; k++){
      float4 w = *reinterpret_cast<const float4*>(W2t + (size_t)k * 256 + m0);
      float4 a = *reinterpret_cast<const float4*>(&aggT[h][k][d0]);
      acc[0][0] += a.x * w.x; acc[0][1] += a.x * w.y; acc[0][2] += a.x * w.z; acc[0][3] += a.x * w.w;
      acc[1][0] += a.y * w.x; acc[1][1] += a.y * w.y; acc[1][2] += a.y * w.z; acc[1][3] += a.y * w.w;
      acc[2][0] += a.z * w.x; acc[2][1] += a.z * w.y; acc[2][2] += a.z * w.z; acc[2][3] += a.z * w.w;
      acc[3][0] += a.w * w.x; acc[3][1] += a.w * w.y; acc[3][2] += a.w * w.z; acc[3][3] += a.w * w.w;
    }
    float4 b = *reinterpret_cast<const float4*>(bias2 + m0);
    #pragma unroll
    for (int i = 0; i < 4; i++){
      float4 v;
      v.x = selu_f(acc[i][0] + b.x);
      v.y = selu_f(acc[i][1] + b.y);
      v.z = selu_f(acc[i][2] + b.z);
      v.w = selu_f(acc[i][3] + b.w);
      *reinterpret_cast<float4*>(&x2s[d0 + i][m0]) = v;
    }
  }
  __syncthreads();

  // ---- el3/er3 (threads 128..143) ----
  if (t >= 128 && t < 144){
    int j = t - 128;
    int d = j & 7, lr = j >> 3;
    const float* V = lr ? V3R : V3L;
    float p = 0.f;
    for (int k = 0; k < 256; k++) p += V[k] * x2s[d][k];
    if (lr) er3[nb0 + d] = p;
    else    el3[nb0 + d] = p;
  }
  // ---- GEMM3: feat3[d][c] = sum_k W3[c][k]*x2[d][k], 4m x 1d tile ----
  if (t < 128){
    int mt = t & 15, d = t >> 4;
    int c0 = mt * 4;
    float a0 = 0.f, a1 = 0.f, a2r = 0.f, a3 = 0.f;
    #pragma unroll 4
    for (int k = 0; k < 256; k++){
      float4 w = *reinterpret_cast<const float4*>(W3t + (size_t)k * 64 + c0);
      float xv = x2s[d][k];
      a0 += xv * w.x; a1 += xv * w.y; a2r += xv * w.z; a3 += xv * w.w;
    }
    float4 o; o.x = a0; o.y = a1; o.z = a2r; o.w = a3;
    *reinterpret_cast<float4*>(feat3 + (size_t)(nb0 + d) * 64 + c0) = o;
  }
}

// ---------------- layer-3 aggregation with precomputed alpha ----------------
__global__ __launch_bounds__(256) void gat_agg3(const float* __restrict__ feat, const float* __restrict__ a3,
                                                const int* __restrict__ rp, const int* __restrict__ csr,
                                                const float* __restrict__ bias,
                                                float* __restrict__ out, int n){
  int node = blockIdx.x * 4 + (threadIdx.x >> 6);
  int t = threadIdx.x & 63;
  if (node >= n) return;
  int s0 = rp[node], s1 = rp[node + 1];
  float acc = 0.f;
  for (int i = s0; i < s1; i++){
    acc += a3[i] * feat[(size_t)csr[i] * 64 + t];
  }
  out[(size_t)node * 64 + t] = selu_f(acc + bias[t]);
}

// ---------------- readout ----------------
__global__ void readout_kernel(const float* __restrict__ x3, const float* __restrict__ score_w,
                               const float* __restrict__ score_b, const int* __restrict__ gids,
                               float* __restrict__ num, float* __restrict__ den, int n){
  int node = blockIdx.x * 4 + (threadIdx.x >> 6);
  int lane = threadIdx.x & 63;
  if (node >= n) return;
  float xv = x3[(size_t)node * 64 + lane];
  float p = xv * score_w[lane];
  #pragma unroll
  for (int off = 32; off; off >>= 1) p += __shfl_xor(p, off);
  float w = 1.f / (1.f + expf(-(p + score_b[0])));
  int g = gids[node];
  atomicAdd(&num[(size_t)g * 64 + lane], w * xv);
  if (lane == 0) atomicAdd(&den[g], w);
}

// ---------------- final MLP ----------------
__global__ __launch_bounds__(128) void mlp_kernel(
    const float* __restrict__ num, const float* __restrict__ den,
    const float* __restrict__ fg,
    const float* __restrict__ w1, const float* __restrict__ b1,
    const float* __restrict__ w2, const float* __restrict__ b2,
    const float* __restrict__ w3, const float* __restrict__ b3,
    float* __restrict__ out, int G){
  __shared__ float z[80];
  __shared__ float h1[128];
  __shared__ float h2[64];
  int t = threadIdx.x;
  for (int g = blockIdx.x; g < G; g += gridDim.x){
    if (t < 64){
      float d = den[g];
      d = (d == 0.f) ? 1.f : d;
      z[t] = num[(size_t)g * 64 + t] / d;
    } else if (t < 80){
      z[t] = fg[(size_t)g * 16 + (t - 64)];
    }
    __syncthreads();
    {
      float a = b1[t];
      for (int k = 0; k < 80; k++) a += z[k] * w1[t * 80 + k];
      h1[t] = selu_f(a);
    }
    __syncthreads();
    if (t < 64){
      float a = b2[t];
      for (int k = 0; k < 128; k++) a += h1[k] * w2[t * 128 + k];
      h2[t] = selu_f(a);
    }
    __syncthreads();
    if (t < 64){
      float p = h2[t] * w3[t];
      #pragma unroll
      for (int off = 32; off; off >>= 1) p += __shfl_down(p, off);
      if (t == 0) out[g] = p + b3[0];
    }
    __syncthreads();
  }
}

// ---------------- launch ----------------
extern "C" void kernel_launch(void* const* d_in, const int* in_sizes, int n_in,
                              void* d_out, int out_size, void* d_ws, size_t ws_size,
                              hipStream_t stream) {
  const float* feats_node  = (const float*)d_in[0];
  const float* feats_graph = (const float*)d_in[1];
  const int*   src         = (const int*)d_in[2];
  const int*   dst         = (const int*)d_in[3];
  const int*   gids        = (const int*)d_in[4];
  const float* fc1_w   = (const float*)d_in[5];
  const float* attn_l1 = (const float*)d_in[6];
  const float* attn_r1 = (const float*)d_in[7];
  const float* bias1   = (const float*)d_in[8];
  const float* fc2_w   = (const float*)d_in[9];
  const float* attn_l2 = (const float*)d_in[10];
  const float* attn_r2 = (const float*)d_in[11];
  const float* bias2   = (const float*)d_in[12];
  const float* fc3_w   = (const float*)d_in[13];
  const float* attn_l3 = (const float*)d_in[14];
  const float* attn_r3 = (const float*)d_in[15];
  const float* bias3   = (const float*)d_in[16];
  const float* score_w = (const float*)d_in[17];
  const float* score_b = (const float*)d_in[18];
  const float* mlp_w1  = (const float*)d_in[19];
  const float* mlp_b1  = (const float*)d_in[20];
  const float* mlp_w2  = (const float*)d_in[21];
  const float* mlp_b2  = (const float*)d_in[22];
  const float* mlp_w3  = (const float*)d_in[23];
  const float* mlp_b3  = (const float*)d_in[24];
  float* out = (float*)d_out;

  char* ws = (char*)d_ws;
  size_t off = 0;
  auto alloc = [&](size_t bytes) -> void* {
    void* p = ws + off;
    off += (bytes + 255) / 256 * 256;
    return p;
  };
  int*   deg   = (int*)alloc((size_t)N_NODES * 4);
  int*   fil   = (int*)alloc((size_t)N_NODES * 4);
  int*   rp    = (int*)alloc((size_t)(N_NODES + 1) * 4);
  int*   bs    = (int*)alloc(256 * 4);
  int*   csr   = (int*)alloc((size_t)N_EDGES * 4);
  float* elbuf = (float*)alloc((size_t)N_NODES * 4 * 4);
  float* erbuf = (float*)alloc((size_t)N_NODES * 4 * 4);
  float* V1L   = (float*)alloc(512 * 4);
  float* V1R   = (float*)alloc(512 * 4);
  float* V2L   = (float*)alloc(1024 * 4);
  float* V2R   = (float*)alloc(1024 * 4);
  float* V3L   = (float*)alloc(256 * 4);
  float* V3R   = (float*)alloc(256 * 4);
  float* W1t   = (float*)alloc(32768 * 4);
  float* W2t   = (float*)alloc(65536 * 4);
  float* W3t   = (float*)alloc(16384 * 4);
  float* num   = (float*)alloc((size_t)N_GRAPHS * 64 * 4);
  float* den   = (float*)alloc((size_t)N_GRAPHS * 4);
  float* A     = (float*)alloc((size_t)N_EDGES * 4 * 4);
  float* feat3 = (float*)alloc((size_t)N_NODES * 64 * 4);
  ushort_t*      x1hi = (ushort_t*)alloc((size_t)N_NODES * 256 * 2);
  unsigned char* x1lo = (unsigned char*)alloc((size_t)N_NODES * 256);
  float* x3 = (float*)x1hi;  // overlay: x1 dead after l2_fused

  zero_i32<<<(N_NODES + 255) / 256, 256, 0, stream>>>(deg, N_NODES);
  zero_i32<<<(N_NODES + 255) / 256, 256, 0, stream>>>(fil, N_NODES);
  zero_i32<<<(N_GRAPHS * 64 + 255) / 256, 256, 0, stream>>>((int*)num, N_GRAPHS * 64);
  zero_i32<<<(N_GRAPHS + 255) / 256, 256, 0, stream>>>((int*)den, N_GRAPHS);

  deg_kernel<<<(N_EDGES + 255) / 256, 256, 0, stream>>>(dst, deg, N_EDGES);
  scan1<<<196, 256, 0, stream>>>(deg, rp, bs, N_NODES);
  scan2<<<1, 256, 0, stream>>>(bs, 196);
  scan3<<<(N_NODES + 255) / 256, 256, 0, stream>>>(rp, bs, N_NODES, N_EDGES);
  fill_csr<<<(N_EDGES + 255) / 256, 256, 0, stream>>>(src, dst, rp, fil, csr, N_EDGES);

  compute_v<<<7, 256, 0, stream>>>(fc1_w, attn_l1, attn_r1, fc2_w, attn_l2, attn_r2,
                                   fc3_w, attn_l3, attn_r3, V1L, V1R, V2L, V2R, V3L, V3R);
  wt_kernel<<<448, 256, 0, stream>>>(fc1_w, fc2_w, fc3_w, W1t, W2t, W3t);
  el_er1<<<N_NODES / 4, 256, 0, stream>>>(feats_node, V1L, V1R, elbuf, erbuf, N_NODES);

  // layer 1
  alpha_h4<<<(N_NODES + 255) / 256, 256, 0, stream>>>(elbuf, erbuf, rp, csr, A, N_NODES);
  l1_fused<<<N_NODES / B1, 512, 0, stream>>>(feats_node, W1t, bias1, A,
                                             V2L, V2R, rp, csr, x1hi, x1lo, elbuf, erbuf);
  // layer 2
  alpha_h4<<<(N_NODES + 255) / 256, 256, 0, stream>>>(elbuf, erbuf, rp, csr, A, N_NODES);
  l2_fused<<<N_NODES / B2, 512, 0, stream>>>(x1hi, x1lo, W2t, bias2, A, W3t,
                                             V3L, V3R, rp, csr, feat3, elbuf, erbuf);
  // layer 3
  alpha_h1<<<(N_NODES + 255) / 256, 256, 0, stream>>>(elbuf, erbuf, rp, csr, A, N_NODES);
  gat_agg3<<<N_NODES / 4, 256, 0, stream>>>(feat3, A, rp, csr, bias3, x3, N_NODES);

  readout_kernel<<<N_NODES / 4, 256, 0, stream>>>(x3, score_w, score_b, gids, num, den, N_NODES);
  mlp_kernel<<<256, 128, 0, stream>>>(num, den, feats_graph,
                                      mlp_w1, mlp_b1, mlp_w2, mlp_b2, mlp_w3, mlp_b3,
                                      out, N_GRAPHS);
}

// Round 7
// 2597.241 us; speedup vs baseline: 6.5795x; 1.0648x over previous
//
#include <hip/hip_runtime.h>
#include <math.h>

#define N_NODES 200000
#define N_EDGES 800000
#define N_GRAPHS 8192
#define B1 16       // dst nodes per block, layer-1 fused
#define B2 8        // dst nodes per block, layer-2 fused

typedef unsigned short ushort_t;

__device__ __forceinline__ float selu_f(float x){
  const float alpha = 1.6732632423543772f;
  const float lam   = 1.0507009873554805f;
  return x > 0.f ? lam * x : lam * alpha * (expf(x) - 1.f);
}

// ---------------- utility ----------------
__global__ void zero_i32(int* p, int n){
  int i = blockIdx.x * 256 + threadIdx.x;
  if (i < n) p[i] = 0;
}

// ---------------- CSR build ----------------
__global__ void deg_kernel(const int* __restrict__ dst, int* __restrict__ deg, int E){
  int e = blockIdx.x * 256 + threadIdx.x;
  if (e < E) atomicAdd(&deg[dst[e]], 1);
}

__global__ void scan1(const int* __restrict__ deg, int* __restrict__ rp, int* __restrict__ bs, int n){
  __shared__ int sh[256];
  int t = threadIdx.x;
  int base = blockIdx.x * 1024;
  int v[4]; int s = 0;
  #pragma unroll
  for (int i = 0; i < 4; i++){
    int idx = base + t * 4 + i;
    v[i] = (idx < n) ? deg[idx] : 0;
    s += v[i];
  }
  sh[t] = s; __syncthreads();
  for (int off = 1; off < 256; off <<= 1){
    int x = (t >= off) ? sh[t - off] : 0;
    __syncthreads();
    sh[t] += x;
    __syncthreads();
  }
  int run = (t == 0) ? 0 : sh[t - 1];
  #pragma unroll
  for (int i = 0; i < 4; i++){
    int idx = base + t * 4 + i;
    if (idx < n) rp[idx] = run;
    run += v[i];
  }
  if (t == 255) bs[blockIdx.x] = sh[255];
}

__global__ void scan2(int* bs, int nb){
  __shared__ int sh[256];
  int t = threadIdx.x;
  sh[t] = (t < nb) ? bs[t] : 0; __syncthreads();
  for (int off = 1; off < 256; off <<= 1){
    int x = (t >= off) ? sh[t - off] : 0;
    __syncthreads();
    sh[t] += x;
    __syncthreads();
  }
  int excl = (t == 0) ? 0 : sh[t - 1];
  if (t < nb) bs[t] = excl;
}

__global__ void scan3(int* rp, const int* __restrict__ bs, int n, int total){
  int i = blockIdx.x * 256 + threadIdx.x;
  if (i < n) rp[i] += bs[i >> 10];
  if (i == 0) rp[n] = total;
}

__global__ void fill_csr(const int* __restrict__ src, const int* __restrict__ dst,
                         const int* __restrict__ rp, int* __restrict__ fil,
                         int* __restrict__ csr, int E){
  int e = blockIdx.x * 256 + threadIdx.x;
  if (e < E){
    int d = dst[e];
    int p = atomicAdd(&fil[d], 1);
    csr[rp[d] + p] = src[e];
  }
}

// ---------------- weight transposes: Wt[k][m] = W[m][k] ----------------
__global__ void wt_kernel(const float* __restrict__ W1, const float* __restrict__ W2,
                          const float* __restrict__ W3,
                          float* __restrict__ W1t, float* __restrict__ W2t,
                          float* __restrict__ W3t){
  int i = blockIdx.x * 256 + threadIdx.x;
  if (i < 32768){
    int k = i >> 8, m = i & 255;
    W1t[i] = W1[(size_t)m * 128 + k];
  } else if (i < 32768 + 65536){
    int j = i - 32768;
    int k = j >> 8, m = j & 255;
    W2t[j] = W2[(size_t)m * 256 + k];
  } else if (i < 32768 + 65536 + 16384){
    int j = i - 32768 - 65536;
    int k = j >> 6, c = j & 63;
    W3t[j] = W3[(size_t)c * 256 + k];
  }
}

// ---------------- V = attn^T W precompute ----------------
__global__ void compute_v(const float* __restrict__ W1, const float* __restrict__ al1, const float* __restrict__ ar1,
                          const float* __restrict__ W2, const float* __restrict__ al2, const float* __restrict__ ar2,
                          const float* __restrict__ W3, const float* __restrict__ al3, const float* __restrict__ ar3,
                          float* __restrict__ V1L, float* __restrict__ V1R,
                          float* __restrict__ V2L, float* __restrict__ V2R,
                          float* __restrict__ V3L, float* __restrict__ V3R){
  int i = blockIdx.x * 256 + threadIdx.x;
  if (i < 512){
    int h = i >> 7, k = i & 127;
    float sl = 0.f, sr = 0.f;
    for (int dd = 0; dd < 64; dd++){
      float w = W1[(size_t)(h * 64 + dd) * 128 + k];
      sl += al1[h * 64 + dd] * w;
      sr += ar1[h * 64 + dd] * w;
    }
    V1L[i] = sl; V1R[i] = sr;
  } else if (i < 1536){
    int j = i - 512;
    int h = j >> 8, k = j & 255;
    float sl = 0.f, sr = 0.f;
    for (int dd = 0; dd < 64; dd++){
      float w = W2[(size_t)(h * 64 + dd) * 256 + k];
      sl += al2[h * 64 + dd] * w;
      sr += ar2[h * 64 + dd] * w;
    }
    V2L[j] = sl; V2R[j] = sr;
  } else if (i < 1792){
    int k = i - 1536;
    float sl = 0.f, sr = 0.f;
    for (int dd = 0; dd < 64; dd++){
      float w = W3[(size_t)dd * 256 + k];
      sl += al3[dd] * w;
      sr += ar3[dd] * w;
    }
    V3L[k] = sl; V3R[k] = sr;
  }
}

// ---------------- el/er for layer 1 ----------------
__global__ __launch_bounds__(256) void el_er1(const float* __restrict__ x0,
                                              const float* __restrict__ V1L, const float* __restrict__ V1R,
                                              float* __restrict__ el1, float* __restrict__ er1, int n){
  __shared__ float vl[512], vr[512];
  int t = threadIdx.x;
  for (int i = t; i < 512; i += 256){ vl[i] = V1L[i]; vr[i] = V1R[i]; }
  __syncthreads();
  int node = blockIdx.x * 4 + (t >> 6);
  int l = t & 63;
  if (node >= n) return;
  float xa = x0[(size_t)node * 128 + l];
  float xb = x0[(size_t)node * 128 + 64 + l];
  #pragma unroll
  for (int h = 0; h < 4; h++){
    float pl = xa * vl[h * 128 + l] + xb * vl[h * 128 + 64 + l];
    float pr = xa * vr[h * 128 + l] + xb * vr[h * 128 + 64 + l];
    #pragma unroll
    for (int off = 32; off; off >>= 1){ pl += __shfl_xor(pl, off); pr += __shfl_xor(pr, off); }
    if (l == 0){ el1[(size_t)node * 4 + h] = pl; er1[(size_t)node * 4 + h] = pr; }
  }
}

// ---------------- alpha kernels ----------------
__global__ __launch_bounds__(256) void alpha_h4(const float* __restrict__ el, const float* __restrict__ er,
                                                const int* __restrict__ rp, const int* __restrict__ csr,
                                                float* __restrict__ a, int n){
  int node = blockIdx.x * 256 + threadIdx.x;
  if (node >= n) return;
  int s0 = rp[node], s1 = rp[node + 1];
  if (s0 >= s1) return;
  float4 erv = *reinterpret_cast<const float4*>(er + (size_t)node * 4);
  float m0 = -1e30f, m1 = -1e30f, m2 = -1e30f, m3 = -1e30f;
  for (int i = s0; i < s1; i++){
    float4 e = *reinterpret_cast<const float4*>(el + (size_t)csr[i] * 4);
    float e0 = e.x + erv.x; e0 = e0 > 0.f ? e0 : 0.2f * e0; m0 = fmaxf(m0, e0);
    float e1 = e.y + erv.y; e1 = e1 > 0.f ? e1 : 0.2f * e1; m1 = fmaxf(m1, e1);
    float e2 = e.z + erv.z; e2 = e2 > 0.f ? e2 : 0.2f * e2; m2 = fmaxf(m2, e2);
    float e3 = e.w + erv.w; e3 = e3 > 0.f ? e3 : 0.2f * e3; m3 = fmaxf(m3, e3);
  }
  float d0 = 0.f, d1 = 0.f, d2 = 0.f, d3 = 0.f;
  for (int i = s0; i < s1; i++){
    float4 e = *reinterpret_cast<const float4*>(el + (size_t)csr[i] * 4);
    float e0 = e.x + erv.x; e0 = e0 > 0.f ? e0 : 0.2f * e0; d0 += expf(e0 - m0);
    float e1 = e.y + erv.y; e1 = e1 > 0.f ? e1 : 0.2f * e1; d1 += expf(e1 - m1);
    float e2 = e.z + erv.z; e2 = e2 > 0.f ? e2 : 0.2f * e2; d2 += expf(e2 - m2);
    float e3 = e.w + erv.w; e3 = e3 > 0.f ? e3 : 0.2f * e3; d3 += expf(e3 - m3);
  }
  d0 = 1.f / d0; d1 = 1.f / d1; d2 = 1.f / d2; d3 = 1.f / d3;
  for (int i = s0; i < s1; i++){
    float4 e = *reinterpret_cast<const float4*>(el + (size_t)csr[i] * 4);
    float4 o;
    float e0 = e.x + erv.x; e0 = e0 > 0.f ? e0 : 0.2f * e0; o.x = expf(e0 - m0) * d0;
    float e1 = e.y + erv.y; e1 = e1 > 0.f ? e1 : 0.2f * e1; o.y = expf(e1 - m1) * d1;
    float e2 = e.z + erv.z; e2 = e2 > 0.f ? e2 : 0.2f * e2; o.z = expf(e2 - m2) * d2;
    float e3 = e.w + erv.w; e3 = e3 > 0.f ? e3 : 0.2f * e3; o.w = expf(e3 - m3) * d3;
    *reinterpret_cast<float4*>(a + (size_t)i * 4) = o;
  }
}

__global__ __launch_bounds__(256) void alpha_h1(const float* __restrict__ el, const float* __restrict__ er,
                                                const int* __restrict__ rp, const int* __restrict__ csr,
                                                float* __restrict__ a, int n){
  int node = blockIdx.x * 256 + threadIdx.x;
  if (node >= n) return;
  int s0 = rp[node], s1 = rp[node + 1];
  if (s0 >= s1) return;
  float erv = er[node];
  float m = -1e30f;
  for (int i = s0; i < s1; i++){
    float e = el[csr[i]] + erv; e = e > 0.f ? e : 0.2f * e; m = fmaxf(m, e);
  }
  float den = 0.f;
  for (int i = s0; i < s1; i++){
    float e = el[csr[i]] + erv; e = e > 0.f ? e : 0.2f * e; den += expf(e - m);
  }
  float inv = 1.f / den;
  for (int i = s0; i < s1; i++){
    float e = el[csr[i]] + erv; e = e > 0.f ? e : 0.2f * e; a[i] = expf(e - m) * inv;
  }
}

// ---------------- FUSED layer 1: gather x0 -> GEMM W1 -> x1(24b) + el2/er2 ----------------
__global__ __launch_bounds__(512, 2) void l1_fused(
    const float* __restrict__ x0, const float* __restrict__ W1t, const float* __restrict__ bias1,
    const float* __restrict__ a1,
    const float* __restrict__ V2L, const float* __restrict__ V2R,
    const int* __restrict__ rp, const int* __restrict__ csr,
    ushort_t* __restrict__ x1hi, unsigned char* __restrict__ x1lo,
    float* __restrict__ el2, float* __restrict__ er2){
  __shared__ float aggT[4][128][20];    // [h][k][d]  40.0 KB
  __shared__ float x1s[16][260];        // 16.6 KB
  int t = threadIdx.x;
  int nb0 = blockIdx.x * B1;

  // ---- gather: half-wave (32 lanes) per dst, float4 cols ----
  {
    int g = t >> 5;                     // dst 0..15
    int c4 = t & 31;                    // col-quad 0..31
    int i0 = rp[nb0 + g], i1 = rp[nb0 + g + 1];
    float accr[4][4] = {{0.f}};         // [head][col]
    int s = (i0 < i1) ? csr[i0] : 0;
    for (int i = i0; i < i1; i++){
      int snext = (i + 1 < i1) ? csr[i + 1] : 0;
      float4 av = *reinterpret_cast<const float4*>(a1 + (size_t)i * 4);
      float4 xv = *reinterpret_cast<const float4*>(x0 + (size_t)s * 128 + c4 * 4);
      accr[0][0] += av.x * xv.x; accr[0][1] += av.x * xv.y; accr[0][2] += av.x * xv.z; accr[0][3] += av.x * xv.w;
      accr[1][0] += av.y * xv.x; accr[1][1] += av.y * xv.y; accr[1][2] += av.y * xv.z; accr[1][3] += av.y * xv.w;
      accr[2][0] += av.z * xv.x; accr[2][1] += av.z * xv.y; accr[2][2] += av.z * xv.z; accr[2][3] += av.z * xv.w;
      accr[3][0] += av.w * xv.x; accr[3][1] += av.w * xv.y; accr[3][2] += av.w * xv.z; accr[3][3] += av.w * xv.w;
      s = snext;
    }
    #pragma unroll
    for (int h = 0; h < 4; h++)
      #pragma unroll
      for (int j = 0; j < 4; j++)
        aggT[h][c4 * 4 + j][g] = accr[h][j];
  }
  __syncthreads();

  // ---- GEMM1: 512 threads; thread = (m-quad mt, d-pair dp) ----
  {
    int mt = t >> 3, dp = t & 7;
    int m0 = mt * 4, h = mt >> 4;
    float acc0[4] = {0.f, 0.f, 0.f, 0.f};
    float acc1[4] = {0.f, 0.f, 0.f, 0.f};
    #pragma unroll 4
    for (int k = 0; k < 128; k++){
      float4 w = *reinterpret_cast<const float4*>(W1t + (size_t)k * 256 + m0);
      float a0 = aggT[h][k][dp];
      float a1v = aggT[h][k][dp + 8];
      acc0[0] += a0 * w.x; acc0[1] += a0 * w.y; acc0[2] += a0 * w.z; acc0[3] += a0 * w.w;
      acc1[0] += a1v * w.x; acc1[1] += a1v * w.y; acc1[2] += a1v * w.z; acc1[3] += a1v * w.w;
    }
    float4 b = *reinterpret_cast<const float4*>(bias1 + m0);
    #pragma unroll
    for (int r = 0; r < 2; r++){
      int d = dp + r * 8;
      float* ac = r ? acc1 : acc0;
      float4 v;
      v.x = selu_f(ac[0] + b.x);
      v.y = selu_f(ac[1] + b.y);
      v.z = selu_f(ac[2] + b.z);
      v.w = selu_f(ac[3] + b.w);
      *reinterpret_cast<float4*>(&x1s[d][m0]) = v;
      unsigned int ux = __float_as_uint(v.x), uy = __float_as_uint(v.y);
      unsigned int uz = __float_as_uint(v.z), uw = __float_as_uint(v.w);
      ushort4 h4; uchar4 l4;
      h4.x = (ushort_t)(ux >> 16); h4.y = (ushort_t)(uy >> 16);
      h4.z = (ushort_t)(uz >> 16); h4.w = (ushort_t)(uw >> 16);
      l4.x = (unsigned char)(ux >> 8); l4.y = (unsigned char)(uy >> 8);
      l4.z = (unsigned char)(uz >> 8); l4.w = (unsigned char)(uw >> 8);
      size_t base = (size_t)(nb0 + d) * 256 + m0;
      *reinterpret_cast<ushort4*>(x1hi + base) = h4;
      *reinterpret_cast<uchar4*>(x1lo + base) = l4;
    }
  }
  __syncthreads();

  // ---- el2/er2 from fp32 x1 tile (float4) ----
  if (t < 128){
    int d = t & 15, hq = (t >> 4) & 3, lr = t >> 6;
    const float* V = lr ? V2R : V2L;
    const float4* Vq = reinterpret_cast<const float4*>(V + hq * 256);
    const float4* Xq = reinterpret_cast<const float4*>(&x1s[d][0]);
    float p = 0.f;
    #pragma unroll 4
    for (int q = 0; q < 64; q++){
      float4 v = Vq[q]; float4 x = Xq[q];
      p += v.x * x.x; p += v.y * x.y; p += v.z * x.z; p += v.w * x.w;
    }
    if (lr) er2[(size_t)(nb0 + d) * 4 + hq] = p;
    else    el2[(size_t)(nb0 + d) * 4 + hq] = p;
  }
}

// ---------------- FUSED layer 2: gather x1(24b) -> GEMM W2 -> x2 -> el3/er3 + feat3 ----------------
__global__ __launch_bounds__(512, 2) void l2_fused(
    const ushort_t* __restrict__ x1hi, const unsigned char* __restrict__ x1lo,
    const float* __restrict__ W2t, const float* __restrict__ bias2,
    const float* __restrict__ a2, const float* __restrict__ W3t,
    const float* __restrict__ V3L, const float* __restrict__ V3R,
    const int* __restrict__ rp, const int* __restrict__ csr,
    float* __restrict__ feat3, float* __restrict__ el3, float* __restrict__ er3){
  __shared__ float aggT[4][256][12];    // [h][k][d]  48.0 KB
  __shared__ float Wst[4160];           // staged W chunks 16.6 KB
  __shared__ float x2s[8][260];         //  8.3 KB
  int t = threadIdx.x;
  int nb0 = blockIdx.x * B2;

  // ---- gather: one wave per dst, ushort4+uchar4 cols ----
  {
    int d = t >> 6;                     // dst 0..7 (wave index)
    int c4 = t & 63;                    // col-quad 0..63
    int i0 = rp[nb0 + d], i1 = rp[nb0 + d + 1];
    float accr[4][4] = {{0.f}};         // [head][col]
    int s = (i0 < i1) ? csr[i0] : 0;
    for (int i = i0; i < i1; i++){
      int snext = (i + 1 < i1) ? csr[i + 1] : 0;
      float4 av = *reinterpret_cast<const float4*>(a2 + (size_t)i * 4);
      ushort4 hv = *reinterpret_cast<const ushort4*>(x1hi + (size_t)s * 256 + c4 * 4);
      uchar4  lv = *reinterpret_cast<const uchar4*>(x1lo + (size_t)s * 256 + c4 * 4);
      float x0v = __uint_as_float(((unsigned int)hv.x << 16) | ((unsigned int)lv.x << 8));
      float x1v = __uint_as_float(((unsigned int)hv.y << 16) | ((unsigned int)lv.y << 8));
      float x2v = __uint_as_float(((unsigned int)hv.z << 16) | ((unsigned int)lv.z << 8));
      float x3v = __uint_as_float(((unsigned int)hv.w << 16) | ((unsigned int)lv.w << 8));
      accr[0][0] += av.x * x0v; accr[0][1] += av.x * x1v; accr[0][2] += av.x * x2v; accr[0][3] += av.x * x3v;
      accr[1][0] += av.y * x0v; accr[1][1] += av.y * x1v; accr[1][2] += av.y * x2v; accr[1][3] += av.y * x3v;
      accr[2][0] += av.z * x0v; accr[2][1] += av.z * x1v; accr[2][2] += av.z * x2v; accr[2][3] += av.z * x3v;
      accr[3][0] += av.w * x0v; accr[3][1] += av.w * x1v; accr[3][2] += av.w * x2v; accr[3][3] += av.w * x3v;
      s = snext;
    }
    #pragma unroll
    for (int h = 0; h < 4; h++)
      #pragma unroll
      for (int j = 0; j < 4; j++)
        aggT[h][c4 * 4 + j][d] = accr[h][j];
  }
  __syncthreads();

  // ---- GEMM2: 512 threads (m-quad mt, d), W2t staged 16 rows at a time ----
  {
    int mt = t >> 3, d2 = t & 7;
    int m0 = mt * 4, h = mt >> 4;
    float acc[4] = {0.f, 0.f, 0.f, 0.f};
    int skr = t >> 5, sm = (t * 8) & 255;
    for (int kc = 0; kc < 16; kc++){
      {
        const float* wsrc = W2t + (size_t)(kc * 16 + skr) * 256 + sm;
        float4 wa = *reinterpret_cast<const float4*>(wsrc);
        float4 wb = *reinterpret_cast<const float4*>(wsrc + 4);
        *reinterpret_cast<float4*>(&Wst[skr * 260 + sm]) = wa;
        *reinterpret_cast<float4*>(&Wst[skr * 260 + sm + 4]) = wb;
      }
      __syncthreads();
      #pragma unroll 4
      for (int kr = 0; kr < 16; kr++){
        int k = kc * 16 + kr;
        float4 w = *reinterpret_cast<const float4*>(&Wst[kr * 260 + m0]);
        float a = aggT[h][k][d2];
        acc[0] += a * w.x; acc[1] += a * w.y; acc[2] += a * w.z; acc[3] += a * w.w;
      }
      __syncthreads();
    }
    float4 b = *reinterpret_cast<const float4*>(bias2 + m0);
    float4 v;
    v.x = selu_f(acc[0] + b.x);
    v.y = selu_f(acc[1] + b.y);
    v.z = selu_f(acc[2] + b.z);
    v.w = selu_f(acc[3] + b.w);
    *reinterpret_cast<float4*>(&x2s[d2][m0]) = v;
  }
  __syncthreads();

  // ---- GEMM3: feat3 = W3 . x2 ; one wave per dst, W3t staged 64 rows at a time ----
  {
    int d3 = t >> 6, c = t & 63;
    float acc = 0.f;
    int skr = t >> 3, sc = (t * 8) & 63;
    for (int kc = 0; kc < 4; kc++){
      __syncthreads();
      {
        const float* wsrc = W3t + (size_t)(kc * 64 + skr) * 64 + sc;
        float4 wa = *reinterpret_cast<const float4*>(wsrc);
        float4 wb = *reinterpret_cast<const float4*>(wsrc + 4);
        *reinterpret_cast<float4*>(&Wst[skr * 64 + sc]) = wa;
        *reinterpret_cast<float4*>(&Wst[skr * 64 + sc + 4]) = wb;
      }
      __syncthreads();
      #pragma unroll 8
      for (int kr = 0; kr < 64; kr++){
        acc += Wst[kr * 64 + c] * x2s[d3][kc * 64 + kr];
      }
    }
    feat3[(size_t)(nb0 + d3) * 64 + c] = acc;
  }

  // ---- el3/er3 from fp32 x2 tile ----
  if (t < 16){
    int d = t & 7, lr = t >> 3;
    const float* V = lr ? V3R : V3L;
    float p = 0.f;
    for (int k = 0; k < 256; k++) p += V[k] * x2s[d][k];
    if (lr) er3[nb0 + d] = p;
    else    el3[nb0 + d] = p;
  }
}

// ---------------- layer-3 aggregation with precomputed alpha ----------------
__global__ __launch_bounds__(256) void gat_agg3(const float* __restrict__ feat, const float* __restrict__ a3,
                                                const int* __restrict__ rp, const int* __restrict__ csr,
                                                const float* __restrict__ bias,
                                                float* __restrict__ out, int n){
  int node = blockIdx.x * 4 + (threadIdx.x >> 6);
  int t = threadIdx.x & 63;
  if (node >= n) return;
  int s0 = rp[node], s1 = rp[node + 1];
  float acc = 0.f;
  int s = (s0 < s1) ? csr[s0] : 0;
  for (int i = s0; i < s1; i++){
    int snext = (i + 1 < s1) ? csr[i + 1] : 0;
    acc += a3[i] * feat[(size_t)s * 64 + t];
    s = snext;
  }
  out[(size_t)node * 64 + t] = selu_f(acc + bias[t]);
}

// ---------------- readout ----------------
__global__ void readout_kernel(const float* __restrict__ x3, const float* __restrict__ score_w,
                               const float* __restrict__ score_b, const int* __restrict__ gids,
                               float* __restrict__ num, float* __restrict__ den, int n){
  int node = blockIdx.x * 4 + (threadIdx.x >> 6);
  int lane = threadIdx.x & 63;
  if (node >= n) return;
  float xv = x3[(size_t)node * 64 + lane];
  float p = xv * score_w[lane];
  #pragma unroll
  for (int off = 32; off; off >>= 1) p += __shfl_xor(p, off);
  float w = 1.f / (1.f + expf(-(p + score_b[0])));
  int g = gids[node];
  atomicAdd(&num[(size_t)g * 64 + lane], w * xv);
  if (lane == 0) atomicAdd(&den[g], w);
}

// ---------------- final MLP ----------------
__global__ __launch_bounds__(128) void mlp_kernel(
    const float* __restrict__ num, const float* __restrict__ den,
    const float* __restrict__ fg,
    const float* __restrict__ w1, const float* __restrict__ b1,
    const float* __restrict__ w2, const float* __restrict__ b2,
    const float* __restrict__ w3, const float* __restrict__ b3,
    float* __restrict__ out, int G){
  __shared__ float z[80];
  __shared__ float h1[128];
  __shared__ float h2[64];
  int t = threadIdx.x;
  for (int g = blockIdx.x; g < G; g += gridDim.x){
    if (t < 64){
      float d = den[g];
      d = (d == 0.f) ? 1.f : d;
      z[t] = num[(size_t)g * 64 + t] / d;
    } else if (t < 80){
      z[t] = fg[(size_t)g * 16 + (t - 64)];
    }
    __syncthreads();
    {
      float a = b1[t];
      for (int k = 0; k < 80; k++) a += z[k] * w1[t * 80 + k];
      h1[t] = selu_f(a);
    }
    __syncthreads();
    if (t < 64){
      float a = b2[t];
      for (int k = 0; k < 128; k++) a += h1[k] * w2[t * 128 + k];
      h2[t] = selu_f(a);
    }
    __syncthreads();
    if (t < 64){
      float p = h2[t] * w3[t];
      #pragma unroll
      for (int off = 32; off; off >>= 1) p += __shfl_down(p, off);
      if (t == 0) out[g] = p + b3[0];
    }
    __syncthreads();
  }
}

// ---------------- launch ----------------
extern "C" void kernel_launch(void* const* d_in, const int* in_sizes, int n_in,
                              void* d_out, int out_size, void* d_ws, size_t ws_size,
                              hipStream_t stream) {
  const float* feats_node  = (const float*)d_in[0];
  const float* feats_graph = (const float*)d_in[1];
  const int*   src         = (const int*)d_in[2];
  const int*   dst         = (const int*)d_in[3];
  const int*   gids        = (const int*)d_in[4];
  const float* fc1_w   = (const float*)d_in[5];
  const float* attn_l1 = (const float*)d_in[6];
  const float* attn_r1 = (const float*)d_in[7];
  const float* bias1   = (const float*)d_in[8];
  const float* fc2_w   = (const float*)d_in[9];
  const float* attn_l2 = (const float*)d_in[10];
  const float* attn_r2 = (const float*)d_in[11];
  const float* bias2   = (const float*)d_in[12];
  const float* fc3_w   = (const float*)d_in[13];
  const float* attn_l3 = (const float*)d_in[14];
  const float* attn_r3 = (const float*)d_in[15];
  const float* bias3   = (const float*)d_in[16];
  const float* score_w = (const float*)d_in[17];
  const float* score_b = (const float*)d_in[18];
  const float* mlp_w1  = (const float*)d_in[19];
  const float* mlp_b1  = (const float*)d_in[20];
  const float* mlp_w2  = (const float*)d_in[21];
  const float* mlp_b2  = (const float*)d_in[22];
  const float* mlp_w3  = (const float*)d_in[23];
  const float* mlp_b3  = (const float*)d_in[24];
  float* out = (float*)d_out;

  char* ws = (char*)d_ws;
  size_t off = 0;
  auto alloc = [&](size_t bytes) -> void* {
    void* p = ws + off;
    off += (bytes + 255) / 256 * 256;
    return p;
  };
  int*   deg   = (int*)alloc((size_t)N_NODES * 4);
  int*   fil   = (int*)alloc((size_t)N_NODES * 4);
  int*   rp    = (int*)alloc((size_t)(N_NODES + 1) * 4);
  int*   bs    = (int*)alloc(256 * 4);
  int*   csr   = (int*)alloc((size_t)N_EDGES * 4);
  float* elbuf = (float*)alloc((size_t)N_NODES * 4 * 4);
  float* erbuf = (float*)alloc((size_t)N_NODES * 4 * 4);
  float* V1L   = (float*)alloc(512 * 4);
  float* V1R   = (float*)alloc(512 * 4);
  float* V2L   = (float*)alloc(1024 * 4);
  float* V2R   = (float*)alloc(1024 * 4);
  float* V3L   = (float*)alloc(256 * 4);
  float* V3R   = (float*)alloc(256 * 4);
  float* W1t   = (float*)alloc(32768 * 4);
  float* W2t   = (float*)alloc(65536 * 4);
  float* W3t   = (float*)alloc(16384 * 4);
  float* num   = (float*)alloc((size_t)N_GRAPHS * 64 * 4);
  float* den   = (float*)alloc((size_t)N_GRAPHS * 4);
  float* A     = (float*)alloc((size_t)N_EDGES * 4 * 4);
  float* feat3 = (float*)alloc((size_t)N_NODES * 64 * 4);
  ushort_t*      x1hi = (ushort_t*)alloc((size_t)N_NODES * 256 * 2);
  unsigned char* x1lo = (unsigned char*)alloc((size_t)N_NODES * 256);
  float* x3 = (float*)x1hi;  // overlay: x1 dead after l2_fused

  zero_i32<<<(N_NODES + 255) / 256, 256, 0, stream>>>(deg, N_NODES);
  zero_i32<<<(N_NODES + 255) / 256, 256, 0, stream>>>(fil, N_NODES);
  zero_i32<<<(N_GRAPHS * 64 + 255) / 256, 256, 0, stream>>>((int*)num, N_GRAPHS * 64);
  zero_i32<<<(N_GRAPHS + 255) / 256, 256, 0, stream>>>((int*)den, N_GRAPHS);

  deg_kernel<<<(N_EDGES + 255) / 256, 256, 0, stream>>>(dst, deg, N_EDGES);
  scan1<<<196, 256, 0, stream>>>(deg, rp, bs, N_NODES);
  scan2<<<1, 256, 0, stream>>>(bs, 196);
  scan3<<<(N_NODES + 255) / 256, 256, 0, stream>>>(rp, bs, N_NODES, N_EDGES);
  fill_csr<<<(N_EDGES + 255) / 256, 256, 0, stream>>>(src, dst, rp, fil, csr, N_EDGES);

  compute_v<<<7, 256, 0, stream>>>(fc1_w, attn_l1, attn_r1, fc2_w, attn_l2, attn_r2,
                                   fc3_w, attn_l3, attn_r3, V1L, V1R, V2L, V2R, V3L, V3R);
  wt_kernel<<<448, 256, 0, stream>>>(fc1_w, fc2_w, fc3_w, W1t, W2t, W3t);
  el_er1<<<N_NODES / 4, 256, 0, stream>>>(feats_node, V1L, V1R, elbuf, erbuf, N_NODES);

  // layer 1
  alpha_h4<<<(N_NODES + 255) / 256, 256, 0, stream>>>(elbuf, erbuf, rp, csr, A, N_NODES);
  l1_fused<<<N_NODES / B1, 512, 0, stream>>>(feats_node, W1t, bias1, A,
                                             V2L, V2R, rp, csr, x1hi, x1lo, elbuf, erbuf);
  // layer 2
  alpha_h4<<<(N_NODES + 255) / 256, 256, 0, stream>>>(elbuf, erbuf, rp, csr, A, N_NODES);
  l2_fused<<<N_NODES / B2, 512, 0, stream>>>(x1hi, x1lo, W2t, bias2, A, W3t,
                                             V3L, V3R, rp, csr, feat3, elbuf, erbuf);
  // layer 3
  alpha_h1<<<(N_NODES + 255) / 256, 256, 0, stream>>>(elbuf, erbuf, rp, csr, A, N_NODES);
  gat_agg3<<<N_NODES / 4, 256, 0, stream>>>(feat3, A, rp, csr, bias3, x3, N_NODES);

  readout_kernel<<<N_NODES / 4, 256, 0, stream>>>(x3, score_w, score_b, gids, num, den, N_NODES);
  mlp_kernel<<<256, 128, 0, stream>>>(num, den, feats_graph,
                                      mlp_w1, mlp_b1, mlp_w2, mlp_b2, mlp_w3, mlp_b3,
                                      out, N_GRAPHS);
}